// Round 1
// baseline (1745.866 us; speedup 1.0000x reference)
//
#include <hip/hip_runtime.h>
#include <cstdint>
#include <cstddef>

#define B8 8
#define LSEQ 2048
#define LC 2051
#define DMODEL 1024
#define DIM 2048
#define LPAD 2054           // 3 + 2048 + 3 zero-padded rows per batch
#define M2 16408            // B8*LC valid rows
#define M2P 16512           // padded to multiple of 128

typedef __attribute__((ext_vector_type(8))) short short8;
typedef __attribute__((ext_vector_type(4))) float floatx4;

__device__ __forceinline__ float bf2f(unsigned short h) {
  union { unsigned int u; float f; } v; v.u = ((unsigned int)h) << 16; return v.f;
}
__device__ __forceinline__ unsigned short f2bf(float f) {
  union { float f; unsigned int u; } v; v.f = f;
  unsigned int r = (v.u + 0x7FFFu + ((v.u >> 16) & 1u)) >> 16;
  return (unsigned short)r;
}

// ---------------- fp32 -> bf16 convert (8 elems/thread) ----------------
__global__ __launch_bounds__(256) void cvt_f32_bf16(const float* __restrict__ in,
                                                    unsigned short* __restrict__ out,
                                                    int n8) {
  int i = blockIdx.x * 256 + threadIdx.x;
  if (i >= n8) return;
  const float4* p = (const float4*)in + (size_t)i * 2;
  float4 a = p[0], b = p[1];
  uint4 o;
  o.x = (unsigned)f2bf(a.x) | ((unsigned)f2bf(a.y) << 16);
  o.y = (unsigned)f2bf(a.z) | ((unsigned)f2bf(a.w) << 16);
  o.z = (unsigned)f2bf(b.x) | ((unsigned)f2bf(b.y) << 16);
  o.w = (unsigned)f2bf(b.z) | ((unsigned)f2bf(b.w) << 16);
  *((uint4*)out + i) = o;
}

// ---------------- zero the 6 pad rows per batch of xp ----------------
__global__ __launch_bounds__(256) void zero_pads(unsigned short* __restrict__ xp) {
  int i = blockIdx.x * 256 + threadIdx.x;      // 0..12287
  int b = i / 1536;
  int r6 = (i % 1536) / 256;
  int dd = (i % 256) * 8;
  int row = (r6 < 3) ? r6 : (2048 + r6);       // 0,1,2,2051,2052,2053
  uint4 z = make_uint4(0, 0, 0, 0);
  *(uint4*)(xp + ((size_t)b * LPAD + row) * DIM + dd) = z;
}

// ---------------- depthwise conv1d: xp(padded bf16) -> xc bf16 ----------------
__global__ __launch_bounds__(256) void conv_kernel(const unsigned short* __restrict__ xp,
                                                   const float* __restrict__ conv_w,
                                                   const float* __restrict__ conv_b,
                                                   unsigned short* __restrict__ xc) {
  const int tc = blockIdx.x, b = blockIdx.y;
  const int d0 = threadIdx.x * 8;
  const unsigned short* base = xp + ((size_t)b * LPAD + tc) * DIM + d0;

  float4 cw[8];
#pragma unroll
  for (int j = 0; j < 8; ++j) cw[j] = *(const float4*)(conv_w + (size_t)(d0 + j) * 4);

  float acc[8];
  const float4* cb4 = (const float4*)(conv_b + d0);
  float4 cb0 = cb4[0], cb1 = cb4[1];
  acc[0] = cb0.x; acc[1] = cb0.y; acc[2] = cb0.z; acc[3] = cb0.w;
  acc[4] = cb1.x; acc[5] = cb1.y; acc[6] = cb1.z; acc[7] = cb1.w;

#pragma unroll
  for (int k = 0; k < 4; ++k) {
    uint4 v = *(const uint4*)(base + (size_t)k * DIM);
    unsigned short e[8];
    e[0] = v.x & 0xffff; e[1] = v.x >> 16; e[2] = v.y & 0xffff; e[3] = v.y >> 16;
    e[4] = v.z & 0xffff; e[5] = v.z >> 16; e[6] = v.w & 0xffff; e[7] = v.w >> 16;
#pragma unroll
    for (int j = 0; j < 8; ++j)
      acc[j] = fmaf(bf2f(e[j]), ((const float*)&cw[j])[k], acc[j]);
  }
  uint4 o;
  o.x = (unsigned)f2bf(acc[0]) | ((unsigned)f2bf(acc[1]) << 16);
  o.y = (unsigned)f2bf(acc[2]) | ((unsigned)f2bf(acc[3]) << 16);
  o.z = (unsigned)f2bf(acc[4]) | ((unsigned)f2bf(acc[5]) << 16);
  o.w = (unsigned)f2bf(acc[6]) | ((unsigned)f2bf(acc[7]) << 16);
  *(uint4*)(xc + ((size_t)b * LC + tc) * DIM + d0) = o;
}

// ---------------- bf16 MFMA GEMM: C = A(MxK) @ B(NxK)^T, m97 structure ----------------
#define GAS(p) ((const __attribute__((address_space(1))) void*)(p))
#define LAS(p) ((__attribute__((address_space(3))) void*)(p))

// MODE 0: gemm1 -> xp padded bf16, +b_in      (M=16384, N=2048)
// MODE 1: xdbl  -> fp32 [M2][48], cols<48     (M=16512, N=128)
// MODE 2: out   -> fp32 [M2][1024], +b_out    (M=16512, N=1024)
template <int MODE>
__global__ __launch_bounds__(256) void gemm_bt(const unsigned short* __restrict__ A,
                                               const unsigned short* __restrict__ Bw,
                                               const float* __restrict__ bias,
                                               void* __restrict__ Cout, int K) {
  __shared__ __align__(16) short As[128 * 32];
  __shared__ __align__(16) short Bs[128 * 32];
  const int tid = threadIdx.x;
  const int lane = tid & 63, wave = tid >> 6;
  const int wr = wave >> 1, wc = wave & 1;
  const int bm = blockIdx.x, bn = blockIdx.y;

  floatx4 acc[4][4];
#pragma unroll
  for (int i = 0; i < 4; ++i)
#pragma unroll
    for (int j = 0; j < 4; ++j) acc[i][j] = (floatx4){0.f, 0.f, 0.f, 0.f};

  const int sr = tid >> 2;             // staging row 0..63
  const int sc = (tid & 3) * 8;        // staging col (elems)
  const unsigned short* Ab = A + (size_t)(bm * 128 + sr) * K + sc;
  const unsigned short* Bb = Bw + (size_t)(bn * 128 + sr) * K + sc;
  const size_t rowK64 = (size_t)64 * K;

  const int fr = lane & 15;
  const int fk = (lane >> 4) * 8;
  const int aoff0 = (wr * 64 + fr) * 32 + fk;
  const int boff0 = (wc * 64 + fr) * 32 + fk;

  for (int k0 = 0; k0 < K; k0 += 32) {
    __syncthreads();  // previous compute done before overwrite
    __builtin_amdgcn_global_load_lds(GAS(Ab + k0),          LAS(As + tid * 8), 16, 0, 0);
    __builtin_amdgcn_global_load_lds(GAS(Ab + rowK64 + k0), LAS(As + 2048 + tid * 8), 16, 0, 0);
    __builtin_amdgcn_global_load_lds(GAS(Bb + k0),          LAS(Bs + tid * 8), 16, 0, 0);
    __builtin_amdgcn_global_load_lds(GAS(Bb + rowK64 + k0), LAS(Bs + 2048 + tid * 8), 16, 0, 0);
    __syncthreads();  // drains vmcnt -> LDS ready

    short8 af[4], bf[4];
#pragma unroll
    for (int mt = 0; mt < 4; ++mt) af[mt] = *(const short8*)&As[aoff0 + mt * 16 * 32];
#pragma unroll
    for (int nt = 0; nt < 4; ++nt) bf[nt] = *(const short8*)&Bs[boff0 + nt * 16 * 32];
#pragma unroll
    for (int mt = 0; mt < 4; ++mt)
#pragma unroll
      for (int nt = 0; nt < 4; ++nt)
        acc[mt][nt] = __builtin_amdgcn_mfma_f32_16x16x32_bf16(af[mt], bf[nt], acc[mt][nt], 0, 0, 0);
  }

  const int er = (lane >> 4) * 4, ec = lane & 15;
#pragma unroll
  for (int mt = 0; mt < 4; ++mt) {
#pragma unroll
    for (int nt = 0; nt < 4; ++nt) {
#pragma unroll
      for (int i = 0; i < 4; ++i) {
        int r = bm * 128 + wr * 64 + mt * 16 + er + i;
        int c = bn * 128 + wc * 64 + nt * 16 + ec;
        float v = acc[mt][nt][i];
        if constexpr (MODE == 0) {
          int bb = r >> 11, t = r & 2047;
          ((unsigned short*)Cout)[((size_t)bb * LPAD + 3 + t) * DIM + c] = f2bf(v + bias[c]);
        } else if constexpr (MODE == 1) {
          if (r < M2 && c < 48) ((float*)Cout)[(size_t)r * 48 + c] = v;
        } else {
          if (r < M2) ((float*)Cout)[(size_t)r * DMODEL + c] = v + bias[c];
        }
      }
    }
  }
}

// ---------------- selective scan: 1 lane per (b,d) chain ----------------
__global__ __launch_bounds__(64) void scan_kernel(const unsigned short* __restrict__ xc,
                                                  const float* __restrict__ xd,
                                                  const float* __restrict__ W_dt,
                                                  const float* __restrict__ b_dt,
                                                  unsigned short* __restrict__ y) {
  const int d = blockIdx.x * 64 + threadIdx.x;
  const int b = blockIdx.y;
  float wdt[16];
#pragma unroll
  for (int n = 0; n < 16; ++n) wdt[n] = W_dt[(size_t)d * 16 + n];
  const float bdt = b_dt[d];
  float Ae[16];
#pragma unroll
  for (int n = 0; n < 16; ++n) Ae[n] = -__expf(-(float)n * (1.0f / 3.0f));
  float h[16];
#pragma unroll
  for (int n = 0; n < 16; ++n) h[n] = 0.f;

  const unsigned short* xcp = xc + ((size_t)b * LC) * DIM + d;
  unsigned short* yp = y + ((size_t)b * LC) * DIM + d;
  const float* xdb = xd + (size_t)b * LC * 48;   // uniform per block -> s_load

  float xdA[48], xdB[48];
#pragma unroll
  for (int j = 0; j < 48; ++j) xdA[j] = xdb[j];
  float c0 = bf2f(xcp[0]);

  auto step = [&](const float (&XD)[48], float xcv, int t) {
    float z0 = bdt, z1 = 0.f, z2 = 0.f, z3 = 0.f;
#pragma unroll
    for (int n = 0; n < 16; n += 4) {
      z0 = fmaf(XD[n + 0], wdt[n + 0], z0);
      z1 = fmaf(XD[n + 1], wdt[n + 1], z1);
      z2 = fmaf(XD[n + 2], wdt[n + 2], z2);
      z3 = fmaf(XD[n + 3], wdt[n + 3], z3);
    }
    float z = (z0 + z1) + (z2 + z3);
    float delta = (z > 20.f) ? z : log1pf(__expf(z));
    float y0 = 0.f, y1 = 0.f, y2 = 0.f, y3 = 0.f;
#pragma unroll
    for (int n = 0; n < 16; n += 4) {
      float e0 = __expf(delta * Ae[n + 0]);
      float e1 = __expf(delta * Ae[n + 1]);
      float e2 = __expf(delta * Ae[n + 2]);
      float e3 = __expf(delta * Ae[n + 3]);
      h[n + 0] = fmaf(h[n + 0], e0, xcv * XD[16 + n + 0]);
      h[n + 1] = fmaf(h[n + 1], e1, xcv * XD[16 + n + 1]);
      h[n + 2] = fmaf(h[n + 2], e2, xcv * XD[16 + n + 2]);
      h[n + 3] = fmaf(h[n + 3], e3, xcv * XD[16 + n + 3]);
      y0 = fmaf(h[n + 0], XD[32 + n + 0], y0);
      y1 = fmaf(h[n + 1], XD[32 + n + 1], y1);
      y2 = fmaf(h[n + 2], XD[32 + n + 2], y2);
      y3 = fmaf(h[n + 3], XD[32 + n + 3], y3);
    }
    yp[(size_t)t * DIM] = f2bf((y0 + y1) + (y2 + y3));
  };

  for (int t = 0; t < LC; t += 2) {
    int t1 = (t + 1 <= LC - 1) ? t + 1 : LC - 1;
    const float* pB = xdb + (size_t)48 * t1;
#pragma unroll
    for (int j = 0; j < 48; ++j) xdB[j] = pB[j];
    float c1 = bf2f(xcp[(size_t)t1 * DIM]);
    step(xdA, c0, t);
    if (t + 1 > LC - 1) break;
    int t2 = (t + 2 <= LC - 1) ? t + 2 : LC - 1;
    const float* pA = xdb + (size_t)48 * t2;
#pragma unroll
    for (int j = 0; j < 48; ++j) xdA[j] = pA[j];
    c0 = bf2f(xcp[(size_t)t2 * DIM]);
    step(xdB, c1, t + 1);
  }
}

// ---------------- launch ----------------
extern "C" void kernel_launch(void* const* d_in, const int* in_sizes, int n_in,
                              void* d_out, int out_size, void* d_ws, size_t ws_size,
                              hipStream_t stream) {
  const float* x      = (const float*)d_in[0];
  const float* W_in   = (const float*)d_in[1];
  const float* b_in   = (const float*)d_in[2];
  const float* conv_w = (const float*)d_in[3];
  const float* conv_b = (const float*)d_in[4];
  const float* W_x    = (const float*)d_in[5];
  const float* W_dt   = (const float*)d_in[6];
  const float* b_dt   = (const float*)d_in[7];
  const float* W_out  = (const float*)d_in[8];
  const float* b_out  = (const float*)d_in[9];

  char* w = (char*)d_ws;
  // region 0: xp (8x2054x2048 bf16, 67.31 MB) -- later reused as y (16512x2048 bf16)
  unsigned short* xp   = (unsigned short*)w;
  unsigned short* ybuf = (unsigned short*)w;
  size_t off = (size_t)M2P * DIM * 2;                                  // 67,633,152
  unsigned short* xcb  = (unsigned short*)(w + off); off += (size_t)M2P * DIM * 2;
  unsigned short* xA   = (unsigned short*)(w + off); off += (size_t)16384 * 1024 * 2;
  unsigned short* wInB = (unsigned short*)(w + off); off += (size_t)2048 * 1024 * 2;
  unsigned short* wOutB= (unsigned short*)(w + off); off += (size_t)1024 * 2048 * 2;
  unsigned short* wXB  = (unsigned short*)(w + off); off += (size_t)128 * 2048 * 2;
  float* xdbl          = (float*)(w + off);          off += (size_t)M2 * 48 * 4;
  (void)ws_size; (void)in_sizes; (void)n_in; (void)out_size;

  cvt_f32_bf16<<<8192, 256, 0, stream>>>(x, xA, 2097152);        // x: 16.78M elems
  cvt_f32_bf16<<<1024, 256, 0, stream>>>(W_in, wInB, 262144);
  cvt_f32_bf16<<<1024, 256, 0, stream>>>(W_out, wOutB, 262144);
  cvt_f32_bf16<<<48,   256, 0, stream>>>(W_x, wXB, 12288);       // rows 48..127 garbage, masked later
  zero_pads<<<48, 256, 0, stream>>>(xp);

  gemm_bt<0><<<dim3(128, 16), 256, 0, stream>>>(xA, wInB, b_in, xp, 1024);
  conv_kernel<<<dim3(LC, B8), 256, 0, stream>>>(xp, conv_w, conv_b, xcb);
  gemm_bt<1><<<dim3(129, 1), 256, 0, stream>>>(xcb, wXB, nullptr, xdbl, 2048);
  scan_kernel<<<dim3(32, B8), 64, 0, stream>>>(xcb, xdbl, W_dt, b_dt, ybuf);
  gemm_bt<2><<<dim3(129, 8), 256, 0, stream>>>(ybuf, wOutB, b_out, (float*)d_out, 2048);
}

// Round 2
// 895.111 us; speedup vs baseline: 1.9504x; 1.9504x over previous
//
#include <hip/hip_runtime.h>
#include <cstdint>
#include <cstddef>

#define B8 8
#define LSEQ 2048
#define LC 2051
#define DMODEL 1024
#define DIM 2048
#define LPAD 2054           // 3 + 2048 + 3 zero-padded rows per batch
#define M2 16408            // B8*LC valid rows
#define M2P 16512           // padded to multiple of 128
#define CS 64               // scan chunk size
#define NCH 33              // ceil(2051/64)

typedef __attribute__((ext_vector_type(8))) short short8;
typedef __attribute__((ext_vector_type(4))) float floatx4;

__device__ __forceinline__ float bf2f(unsigned short h) {
  union { unsigned int u; float f; } v; v.u = ((unsigned int)h) << 16; return v.f;
}
__device__ __forceinline__ unsigned short f2bf(float f) {
  union { float f; unsigned int u; } v; v.f = f;
  unsigned int r = (v.u + 0x7FFFu + ((v.u >> 16) & 1u)) >> 16;
  return (unsigned short)r;
}

// ---------------- fp32 -> bf16 convert (8 elems/thread) ----------------
__global__ __launch_bounds__(256) void cvt_f32_bf16(const float* __restrict__ in,
                                                    unsigned short* __restrict__ out,
                                                    int n8) {
  int i = blockIdx.x * 256 + threadIdx.x;
  if (i >= n8) return;
  const float4* p = (const float4*)in + (size_t)i * 2;
  float4 a = p[0], b = p[1];
  uint4 o;
  o.x = (unsigned)f2bf(a.x) | ((unsigned)f2bf(a.y) << 16);
  o.y = (unsigned)f2bf(a.z) | ((unsigned)f2bf(a.w) << 16);
  o.z = (unsigned)f2bf(b.x) | ((unsigned)f2bf(b.y) << 16);
  o.w = (unsigned)f2bf(b.z) | ((unsigned)f2bf(b.w) << 16);
  *((uint4*)out + i) = o;
}

// ---------------- zero the 6 pad rows per batch of xp ----------------
__global__ __launch_bounds__(256) void zero_pads(unsigned short* __restrict__ xp) {
  int i = blockIdx.x * 256 + threadIdx.x;      // 0..12287
  int b = i / 1536;
  int r6 = (i % 1536) / 256;
  int dd = (i % 256) * 8;
  int row = (r6 < 3) ? r6 : (2048 + r6);       // 0,1,2,2051,2052,2053
  uint4 z = make_uint4(0, 0, 0, 0);
  *(uint4*)(xp + ((size_t)b * LPAD + row) * DIM + dd) = z;
}

// ---------------- depthwise conv1d: xp(padded bf16) -> xc bf16 ----------------
__global__ __launch_bounds__(256) void conv_kernel(const unsigned short* __restrict__ xp,
                                                   const float* __restrict__ conv_w,
                                                   const float* __restrict__ conv_b,
                                                   unsigned short* __restrict__ xc) {
  const int tc = blockIdx.x, b = blockIdx.y;
  const int d0 = threadIdx.x * 8;
  const unsigned short* base = xp + ((size_t)b * LPAD + tc) * DIM + d0;

  float4 cw[8];
#pragma unroll
  for (int j = 0; j < 8; ++j) cw[j] = *(const float4*)(conv_w + (size_t)(d0 + j) * 4);

  float acc[8];
  const float4* cb4 = (const float4*)(conv_b + d0);
  float4 cb0 = cb4[0], cb1 = cb4[1];
  acc[0] = cb0.x; acc[1] = cb0.y; acc[2] = cb0.z; acc[3] = cb0.w;
  acc[4] = cb1.x; acc[5] = cb1.y; acc[6] = cb1.z; acc[7] = cb1.w;

#pragma unroll
  for (int k = 0; k < 4; ++k) {
    uint4 v = *(const uint4*)(base + (size_t)k * DIM);
    unsigned short e[8];
    e[0] = v.x & 0xffff; e[1] = v.x >> 16; e[2] = v.y & 0xffff; e[3] = v.y >> 16;
    e[4] = v.z & 0xffff; e[5] = v.z >> 16; e[6] = v.w & 0xffff; e[7] = v.w >> 16;
#pragma unroll
    for (int j = 0; j < 8; ++j)
      acc[j] = fmaf(bf2f(e[j]), ((const float*)&cw[j])[k], acc[j]);
  }
  uint4 o;
  o.x = (unsigned)f2bf(acc[0]) | ((unsigned)f2bf(acc[1]) << 16);
  o.y = (unsigned)f2bf(acc[2]) | ((unsigned)f2bf(acc[3]) << 16);
  o.z = (unsigned)f2bf(acc[4]) | ((unsigned)f2bf(acc[5]) << 16);
  o.w = (unsigned)f2bf(acc[6]) | ((unsigned)f2bf(acc[7]) << 16);
  *(uint4*)(xc + ((size_t)b * LC + tc) * DIM + d0) = o;
}

// ---------------- bf16 MFMA GEMM: C = A(MxK) @ B(NxK)^T, m97 structure ----------------
#define GAS(p) ((const __attribute__((address_space(1))) void*)(p))
#define LAS(p) ((__attribute__((address_space(3))) void*)(p))

// MODE 0: gemm1 -> xp padded bf16, +b_in      (M=16384, N=2048)
// MODE 1: xdbl  -> fp32 [M2][48], cols<48     (M=16512, N=128)
// MODE 2: out   -> fp32 [M2][1024], +b_out    (M=16512, N=1024)
template <int MODE>
__global__ __launch_bounds__(256) void gemm_bt(const unsigned short* __restrict__ A,
                                               const unsigned short* __restrict__ Bw,
                                               const float* __restrict__ bias,
                                               void* __restrict__ Cout, int K) {
  __shared__ __align__(16) short As[128 * 32];
  __shared__ __align__(16) short Bs[128 * 32];
  const int tid = threadIdx.x;
  const int lane = tid & 63, wave = tid >> 6;
  const int wr = wave >> 1, wc = wave & 1;
  const int bm = blockIdx.x, bn = blockIdx.y;

  floatx4 acc[4][4];
#pragma unroll
  for (int i = 0; i < 4; ++i)
#pragma unroll
    for (int j = 0; j < 4; ++j) acc[i][j] = (floatx4){0.f, 0.f, 0.f, 0.f};

  const int sr = tid >> 2;             // staging row 0..63
  const int sc = (tid & 3) * 8;        // staging col (elems)
  const unsigned short* Ab = A + (size_t)(bm * 128 + sr) * K + sc;
  const unsigned short* Bb = Bw + (size_t)(bn * 128 + sr) * K + sc;
  const size_t rowK64 = (size_t)64 * K;

  const int fr = lane & 15;
  const int fk = (lane >> 4) * 8;
  const int aoff0 = (wr * 64 + fr) * 32 + fk;
  const int boff0 = (wc * 64 + fr) * 32 + fk;

  for (int k0 = 0; k0 < K; k0 += 32) {
    __syncthreads();  // previous compute done before overwrite
    __builtin_amdgcn_global_load_lds(GAS(Ab + k0),          LAS(As + tid * 8), 16, 0, 0);
    __builtin_amdgcn_global_load_lds(GAS(Ab + rowK64 + k0), LAS(As + 2048 + tid * 8), 16, 0, 0);
    __builtin_amdgcn_global_load_lds(GAS(Bb + k0),          LAS(Bs + tid * 8), 16, 0, 0);
    __builtin_amdgcn_global_load_lds(GAS(Bb + rowK64 + k0), LAS(Bs + 2048 + tid * 8), 16, 0, 0);
    __syncthreads();  // drains vmcnt -> LDS ready

    short8 af[4], bf[4];
#pragma unroll
    for (int mt = 0; mt < 4; ++mt) af[mt] = *(const short8*)&As[aoff0 + mt * 16 * 32];
#pragma unroll
    for (int nt = 0; nt < 4; ++nt) bf[nt] = *(const short8*)&Bs[boff0 + nt * 16 * 32];
#pragma unroll
    for (int mt = 0; mt < 4; ++mt)
#pragma unroll
      for (int nt = 0; nt < 4; ++nt)
        acc[mt][nt] = __builtin_amdgcn_mfma_f32_16x16x32_bf16(af[mt], bf[nt], acc[mt][nt], 0, 0, 0);
  }

  const int er = (lane >> 4) * 4, ec = lane & 15;
#pragma unroll
  for (int mt = 0; mt < 4; ++mt) {
#pragma unroll
    for (int nt = 0; nt < 4; ++nt) {
#pragma unroll
      for (int i = 0; i < 4; ++i) {
        int r = bm * 128 + wr * 64 + mt * 16 + er + i;
        int c = bn * 128 + wc * 64 + nt * 16 + ec;
        float v = acc[mt][nt][i];
        if constexpr (MODE == 0) {
          int bb = r >> 11, t = r & 2047;
          ((unsigned short*)Cout)[((size_t)bb * LPAD + 3 + t) * DIM + c] = f2bf(v + bias[c]);
        } else if constexpr (MODE == 1) {
          if (r < M2 && c < 48) ((float*)Cout)[(size_t)r * 48 + c] = v;
        } else {
          if (r < M2) ((float*)Cout)[(size_t)r * DMODEL + c] = v + bias[c];
        }
      }
    }
  }
}

// ---------------- chunked scan, pass 1: per-chunk (P, q) ----------------
// One lane per (b,d) chain, one block-y per chunk. q = recurrence from h=0;
// decay product collapses to exp(A[n] * sum(delta)).
__global__ __launch_bounds__(64) void scan_pass1(const unsigned short* __restrict__ xc,
                                                 const float* __restrict__ xd,
                                                 const float* __restrict__ W_dt,
                                                 const float* __restrict__ b_dt,
                                                 float* __restrict__ Pbuf,
                                                 float* __restrict__ qbuf) {
  const int d = blockIdx.x * 64 + threadIdx.x;
  const int c = blockIdx.y, b = blockIdx.z;
  const int t0 = c * CS;
  const int nst = (t0 + CS <= LC) ? CS : (LC - t0);

  float wdt[16];
#pragma unroll
  for (int n = 0; n < 16; ++n) wdt[n] = W_dt[(size_t)d * 16 + n];
  const float bdt = b_dt[d];
  float Ae[16];
#pragma unroll
  for (int n = 0; n < 16; ++n) Ae[n] = -__expf(-(float)n * (1.0f / 3.0f));
  float h[16];
#pragma unroll
  for (int n = 0; n < 16; ++n) h[n] = 0.f;
  float sumd = 0.f;

  const float* xdb = xd + ((size_t)b * LC + t0) * 48;
  const unsigned short* xcp = xc + ((size_t)b * LC + t0) * DIM + d;

  float XA[32], XB[32];
#pragma unroll
  for (int j = 0; j < 32; ++j) XA[j] = xdb[j];
  float c0 = bf2f(xcp[0]);

  auto step = [&](const float (&XD)[32], float xcv) {
    float z0 = bdt, z1 = 0.f, z2 = 0.f, z3 = 0.f;
#pragma unroll
    for (int n = 0; n < 16; n += 4) {
      z0 = fmaf(XD[n + 0], wdt[n + 0], z0);
      z1 = fmaf(XD[n + 1], wdt[n + 1], z1);
      z2 = fmaf(XD[n + 2], wdt[n + 2], z2);
      z3 = fmaf(XD[n + 3], wdt[n + 3], z3);
    }
    float z = (z0 + z1) + (z2 + z3);
    float delta = (z > 20.f) ? z : log1pf(__expf(z));
    sumd += delta;
#pragma unroll
    for (int n = 0; n < 16; ++n) {
      float e = __expf(delta * Ae[n]);
      h[n] = fmaf(h[n], e, xcv * XD[16 + n]);
    }
  };

  for (int s = 0; s < nst; s += 2) {
    int s1 = (s + 1 < nst) ? s + 1 : s;
#pragma unroll
    for (int j = 0; j < 32; ++j) XB[j] = xdb[(size_t)s1 * 48 + j];
    float c1 = bf2f(xcp[(size_t)s1 * DIM]);
    step(XA, c0);
    if (s + 1 >= nst) break;
    int s2 = (s + 2 < nst) ? s + 2 : s + 1;
#pragma unroll
    for (int j = 0; j < 32; ++j) XA[j] = xdb[(size_t)s2 * 48 + j];
    c0 = bf2f(xcp[(size_t)s2 * DIM]);
    step(XB, c1);
  }

  const size_t base = ((size_t)(b * NCH + c) * 16) * 2048 + d;
#pragma unroll
  for (int n = 0; n < 16; ++n) Pbuf[base + (size_t)n * 2048] = __expf(sumd * Ae[n]);
#pragma unroll
  for (int n = 0; n < 16; ++n) qbuf[base + (size_t)n * 2048] = h[n];
}

// ---------------- boundary scan: h across chunks; writes h_init over q ----------------
__global__ __launch_bounds__(64) void scan_boundary(const float* __restrict__ Pbuf,
                                                    float* __restrict__ qbuf) {
  const int d = blockIdx.x * 64 + threadIdx.x;
  const int b = blockIdx.y;
  float h[16];
#pragma unroll
  for (int n = 0; n < 16; ++n) h[n] = 0.f;
  for (int c = 0; c < NCH; ++c) {
    const size_t base = ((size_t)(b * NCH + c) * 16) * 2048 + d;
    float Pv[16], qv[16];
#pragma unroll
    for (int n = 0; n < 16; ++n) Pv[n] = Pbuf[base + (size_t)n * 2048];
#pragma unroll
    for (int n = 0; n < 16; ++n) qv[n] = qbuf[base + (size_t)n * 2048];
#pragma unroll
    for (int n = 0; n < 16; ++n) {
      qbuf[base + (size_t)n * 2048] = h[n];       // h at chunk start
      h[n] = fmaf(Pv[n], h[n], qv[n]);
    }
  }
}

// ---------------- chunked scan, pass 2: recompute with h_init, emit y ----------------
__global__ __launch_bounds__(64) void scan_pass2(const unsigned short* __restrict__ xc,
                                                 const float* __restrict__ xd,
                                                 const float* __restrict__ W_dt,
                                                 const float* __restrict__ b_dt,
                                                 const float* __restrict__ hinit,
                                                 unsigned short* __restrict__ y) {
  const int d = blockIdx.x * 64 + threadIdx.x;
  const int c = blockIdx.y, b = blockIdx.z;
  const int t0 = c * CS;
  const int nst = (t0 + CS <= LC) ? CS : (LC - t0);

  float wdt[16];
#pragma unroll
  for (int n = 0; n < 16; ++n) wdt[n] = W_dt[(size_t)d * 16 + n];
  const float bdt = b_dt[d];
  float Ae[16];
#pragma unroll
  for (int n = 0; n < 16; ++n) Ae[n] = -__expf(-(float)n * (1.0f / 3.0f));

  const size_t base = ((size_t)(b * NCH + c) * 16) * 2048 + d;
  float h[16];
#pragma unroll
  for (int n = 0; n < 16; ++n) h[n] = hinit[base + (size_t)n * 2048];

  const float* xdb = xd + ((size_t)b * LC + t0) * 48;
  const unsigned short* xcp = xc + ((size_t)b * LC + t0) * DIM + d;
  unsigned short* yp = y + ((size_t)b * LC + t0) * DIM + d;

  float XA[48], XB[48];
#pragma unroll
  for (int j = 0; j < 48; ++j) XA[j] = xdb[j];
  float c0 = bf2f(xcp[0]);

  auto step = [&](const float (&XD)[48], float xcv, int s) {
    float z0 = bdt, z1 = 0.f, z2 = 0.f, z3 = 0.f;
#pragma unroll
    for (int n = 0; n < 16; n += 4) {
      z0 = fmaf(XD[n + 0], wdt[n + 0], z0);
      z1 = fmaf(XD[n + 1], wdt[n + 1], z1);
      z2 = fmaf(XD[n + 2], wdt[n + 2], z2);
      z3 = fmaf(XD[n + 3], wdt[n + 3], z3);
    }
    float z = (z0 + z1) + (z2 + z3);
    float delta = (z > 20.f) ? z : log1pf(__expf(z));
    float y0 = 0.f, y1 = 0.f, y2 = 0.f, y3 = 0.f;
#pragma unroll
    for (int n = 0; n < 16; n += 4) {
      float e0 = __expf(delta * Ae[n + 0]);
      float e1 = __expf(delta * Ae[n + 1]);
      float e2 = __expf(delta * Ae[n + 2]);
      float e3 = __expf(delta * Ae[n + 3]);
      h[n + 0] = fmaf(h[n + 0], e0, xcv * XD[16 + n + 0]);
      h[n + 1] = fmaf(h[n + 1], e1, xcv * XD[16 + n + 1]);
      h[n + 2] = fmaf(h[n + 2], e2, xcv * XD[16 + n + 2]);
      h[n + 3] = fmaf(h[n + 3], e3, xcv * XD[16 + n + 3]);
      y0 = fmaf(h[n + 0], XD[32 + n + 0], y0);
      y1 = fmaf(h[n + 1], XD[32 + n + 1], y1);
      y2 = fmaf(h[n + 2], XD[32 + n + 2], y2);
      y3 = fmaf(h[n + 3], XD[32 + n + 3], y3);
    }
    yp[(size_t)s * DIM] = f2bf((y0 + y1) + (y2 + y3));
  };

  for (int s = 0; s < nst; s += 2) {
    int s1 = (s + 1 < nst) ? s + 1 : s;
#pragma unroll
    for (int j = 0; j < 48; ++j) XB[j] = xdb[(size_t)s1 * 48 + j];
    float c1 = bf2f(xcp[(size_t)s1 * DIM]);
    step(XA, c0, s);
    if (s + 1 >= nst) break;
    int s2 = (s + 2 < nst) ? s + 2 : s + 1;
#pragma unroll
    for (int j = 0; j < 48; ++j) XA[j] = xdb[(size_t)s2 * 48 + j];
    c0 = bf2f(xcp[(size_t)s2 * DIM]);
    step(XB, c1, s + 1);
  }
}

// ---------------- launch ----------------
extern "C" void kernel_launch(void* const* d_in, const int* in_sizes, int n_in,
                              void* d_out, int out_size, void* d_ws, size_t ws_size,
                              hipStream_t stream) {
  const float* x      = (const float*)d_in[0];
  const float* W_in   = (const float*)d_in[1];
  const float* b_in   = (const float*)d_in[2];
  const float* conv_w = (const float*)d_in[3];
  const float* conv_b = (const float*)d_in[4];
  const float* W_x    = (const float*)d_in[5];
  const float* W_dt   = (const float*)d_in[6];
  const float* b_dt   = (const float*)d_in[7];
  const float* W_out  = (const float*)d_in[8];
  const float* b_out  = (const float*)d_in[9];

  char* w = (char*)d_ws;
  // region 0: xp (8x2054x2048 bf16) -- later reused as y (16512x2048 bf16)
  unsigned short* xp   = (unsigned short*)w;
  unsigned short* ybuf = (unsigned short*)w;
  size_t off = (size_t)M2P * DIM * 2;                                  // 67,633,152
  unsigned short* xcb  = (unsigned short*)(w + off); off += (size_t)M2P * DIM * 2;
  size_t xA_off = off;                                                 // 135,266,304
  unsigned short* xA   = (unsigned short*)(w + off); off += (size_t)16384 * 1024 * 2;
  unsigned short* wInB = (unsigned short*)(w + off); off += (size_t)2048 * 1024 * 2;
  unsigned short* wOutB= (unsigned short*)(w + off); off += (size_t)1024 * 2048 * 2;
  unsigned short* wXB  = (unsigned short*)(w + off); off += (size_t)128 * 2048 * 2;
  float* xdbl          = (float*)(w + off);          off += (size_t)M2 * 48 * 4;
  // Pbuf reuses xA+wInB region (dead after gemm1): needs 16384*33*16*4 = 34.6 MB < 37.75 MB
  float* Pbuf          = (float*)(w + xA_off);
  // qbuf: fresh region at the end (34.6 MB); boundary kernel overwrites it with h_init
  float* qbuf          = (float*)(w + off);          off += (size_t)16384 * NCH * 16 * 4;
  (void)ws_size; (void)in_sizes; (void)n_in; (void)out_size;

  cvt_f32_bf16<<<8192, 256, 0, stream>>>(x, xA, 2097152);        // x: 16.78M elems
  cvt_f32_bf16<<<1024, 256, 0, stream>>>(W_in, wInB, 262144);
  cvt_f32_bf16<<<1024, 256, 0, stream>>>(W_out, wOutB, 262144);
  cvt_f32_bf16<<<48,   256, 0, stream>>>(W_x, wXB, 12288);       // rows 48..127 garbage, masked later
  zero_pads<<<48, 256, 0, stream>>>(xp);

  gemm_bt<0><<<dim3(128, 16), 256, 0, stream>>>(xA, wInB, b_in, xp, 1024);
  conv_kernel<<<dim3(LC, B8), 256, 0, stream>>>(xp, conv_w, conv_b, xcb);
  gemm_bt<1><<<dim3(129, 1), 256, 0, stream>>>(xcb, wXB, nullptr, xdbl, 2048);

  scan_pass1<<<dim3(32, NCH, B8), 64, 0, stream>>>(xcb, xdbl, W_dt, b_dt, Pbuf, qbuf);
  scan_boundary<<<dim3(32, B8), 64, 0, stream>>>(Pbuf, qbuf);
  scan_pass2<<<dim3(32, NCH, B8), 64, 0, stream>>>(xcb, xdbl, W_dt, b_dt, qbuf, ybuf);

  gemm_bt<2><<<dim3(129, 8), 256, 0, stream>>>(ybuf, wOutB, b_out, (float*)d_out, 2048);
}

// Round 3
// 688.918 us; speedup vs baseline: 2.5342x; 1.2993x over previous
//
#include <hip/hip_runtime.h>
#include <cstdint>
#include <cstddef>

#define B8 8
#define LSEQ 2048
#define LC 2051
#define DMODEL 1024
#define DIM 2048
#define LPAD 2054           // 3 + 2048 + 3 zero-padded rows per batch
#define M2 16408            // B8*LC valid rows
#define M2P 16512           // padded to multiple of 128
#define CS 64               // scan chunk size
#define NCH 33              // ceil(2051/64)

typedef __attribute__((ext_vector_type(8))) short short8;
typedef __attribute__((ext_vector_type(4))) float floatx4;

// A_n = -exp(-n/3), n=0..15 (compile-time literals)
__device__ __constant__ float AeT[16] = {
  -1.0f,          -0.71653131f, -0.51341712f, -0.36787944f,
  -0.26359714f,   -0.18887560f, -0.13533528f, -0.09697208f,
  -0.06948345f,   -0.04978707f, -0.03567399f, -0.02556154f,
  -0.01831564f,   -0.01312373f, -0.00940356f, -0.00673795f};

__device__ __forceinline__ float bf2f(unsigned short h) {
  union { unsigned int u; float f; } v; v.u = ((unsigned int)h) << 16; return v.f;
}
__device__ __forceinline__ unsigned short f2bf(float f) {
  union { float f; unsigned int u; } v; v.f = f;
  unsigned int r = (v.u + 0x7FFFu + ((v.u >> 16) & 1u)) >> 16;
  return (unsigned short)r;
}

// ---------------- fp32 -> bf16 convert (8 elems/thread) ----------------
__global__ __launch_bounds__(256) void cvt_f32_bf16(const float* __restrict__ in,
                                                    unsigned short* __restrict__ out,
                                                    int n8) {
  int i = blockIdx.x * 256 + threadIdx.x;
  if (i >= n8) return;
  const float4* p = (const float4*)in + (size_t)i * 2;
  float4 a = p[0], b = p[1];
  uint4 o;
  o.x = (unsigned)f2bf(a.x) | ((unsigned)f2bf(a.y) << 16);
  o.y = (unsigned)f2bf(a.z) | ((unsigned)f2bf(a.w) << 16);
  o.z = (unsigned)f2bf(b.x) | ((unsigned)f2bf(b.y) << 16);
  o.w = (unsigned)f2bf(b.z) | ((unsigned)f2bf(b.w) << 16);
  *((uint4*)out + i) = o;
}

// ---------------- zero the 6 pad rows per batch of xp ----------------
__global__ __launch_bounds__(256) void zero_pads(unsigned short* __restrict__ xp) {
  int i = blockIdx.x * 256 + threadIdx.x;      // 0..12287
  int b = i / 1536;
  int r6 = (i % 1536) / 256;
  int dd = (i % 256) * 8;
  int row = (r6 < 3) ? r6 : (2048 + r6);       // 0,1,2,2051,2052,2053
  uint4 z = make_uint4(0, 0, 0, 0);
  *(uint4*)(xp + ((size_t)b * LPAD + row) * DIM + dd) = z;
}

// ---------------- depthwise conv1d: xp(padded bf16) -> xc bf16 ----------------
__global__ __launch_bounds__(256) void conv_kernel(const unsigned short* __restrict__ xp,
                                                   const float* __restrict__ conv_w,
                                                   const float* __restrict__ conv_b,
                                                   unsigned short* __restrict__ xc) {
  const int tc = blockIdx.x, b = blockIdx.y;
  const int d0 = threadIdx.x * 8;
  const unsigned short* base = xp + ((size_t)b * LPAD + tc) * DIM + d0;

  float4 cw[8];
#pragma unroll
  for (int j = 0; j < 8; ++j) cw[j] = *(const float4*)(conv_w + (size_t)(d0 + j) * 4);

  float acc[8];
  const float4* cb4 = (const float4*)(conv_b + d0);
  float4 cb0 = cb4[0], cb1 = cb4[1];
  acc[0] = cb0.x; acc[1] = cb0.y; acc[2] = cb0.z; acc[3] = cb0.w;
  acc[4] = cb1.x; acc[5] = cb1.y; acc[6] = cb1.z; acc[7] = cb1.w;

#pragma unroll
  for (int k = 0; k < 4; ++k) {
    uint4 v = *(const uint4*)(base + (size_t)k * DIM);
    unsigned short e[8];
    e[0] = v.x & 0xffff; e[1] = v.x >> 16; e[2] = v.y & 0xffff; e[3] = v.y >> 16;
    e[4] = v.z & 0xffff; e[5] = v.z >> 16; e[6] = v.w & 0xffff; e[7] = v.w >> 16;
#pragma unroll
    for (int j = 0; j < 8; ++j)
      acc[j] = fmaf(bf2f(e[j]), ((const float*)&cw[j])[k], acc[j]);
  }
  uint4 o;
  o.x = (unsigned)f2bf(acc[0]) | ((unsigned)f2bf(acc[1]) << 16);
  o.y = (unsigned)f2bf(acc[2]) | ((unsigned)f2bf(acc[3]) << 16);
  o.z = (unsigned)f2bf(acc[4]) | ((unsigned)f2bf(acc[5]) << 16);
  o.w = (unsigned)f2bf(acc[6]) | ((unsigned)f2bf(acc[7]) << 16);
  *(uint4*)(xc + ((size_t)b * LC + tc) * DIM + d0) = o;
}

// ---------------- bf16 MFMA GEMM: C = A(MxK) @ B(NxK)^T, m97 structure ----------------
#define GAS(p) ((const __attribute__((address_space(1))) void*)(p))
#define LAS(p) ((__attribute__((address_space(3))) void*)(p))

// MODE 0: gemm1 -> xp padded bf16, +b_in      (M=16384, N=2048)
// MODE 1: xdbl  -> fp32 [M2][48], cols<48     (M=16512, N=128)
// MODE 2: out   -> fp32 [M2][1024], +b_out    (M=16512, N=1024)
template <int MODE>
__global__ __launch_bounds__(256) void gemm_bt(const unsigned short* __restrict__ A,
                                               const unsigned short* __restrict__ Bw,
                                               const float* __restrict__ bias,
                                               void* __restrict__ Cout, int K) {
  __shared__ __align__(16) short As[128 * 32];
  __shared__ __align__(16) short Bs[128 * 32];
  const int tid = threadIdx.x;
  const int lane = tid & 63, wave = tid >> 6;
  const int wr = wave >> 1, wc = wave & 1;
  const int bm = blockIdx.x, bn = blockIdx.y;

  floatx4 acc[4][4];
#pragma unroll
  for (int i = 0; i < 4; ++i)
#pragma unroll
    for (int j = 0; j < 4; ++j) acc[i][j] = (floatx4){0.f, 0.f, 0.f, 0.f};

  const int sr = tid >> 2;             // staging row 0..63
  const int sc = (tid & 3) * 8;        // staging col (elems)
  const unsigned short* Ab = A + (size_t)(bm * 128 + sr) * K + sc;
  const unsigned short* Bb = Bw + (size_t)(bn * 128 + sr) * K + sc;
  const size_t rowK64 = (size_t)64 * K;

  const int fr = lane & 15;
  const int fk = (lane >> 4) * 8;
  const int aoff0 = (wr * 64 + fr) * 32 + fk;
  const int boff0 = (wc * 64 + fr) * 32 + fk;

  for (int k0 = 0; k0 < K; k0 += 32) {
    __syncthreads();  // previous compute done before overwrite
    __builtin_amdgcn_global_load_lds(GAS(Ab + k0),          LAS(As + tid * 8), 16, 0, 0);
    __builtin_amdgcn_global_load_lds(GAS(Ab + rowK64 + k0), LAS(As + 2048 + tid * 8), 16, 0, 0);
    __builtin_amdgcn_global_load_lds(GAS(Bb + k0),          LAS(Bs + tid * 8), 16, 0, 0);
    __builtin_amdgcn_global_load_lds(GAS(Bb + rowK64 + k0), LAS(Bs + 2048 + tid * 8), 16, 0, 0);
    __syncthreads();  // drains vmcnt -> LDS ready

    short8 af[4], bf[4];
#pragma unroll
    for (int mt = 0; mt < 4; ++mt) af[mt] = *(const short8*)&As[aoff0 + mt * 16 * 32];
#pragma unroll
    for (int nt = 0; nt < 4; ++nt) bf[nt] = *(const short8*)&Bs[boff0 + nt * 16 * 32];
#pragma unroll
    for (int mt = 0; mt < 4; ++mt)
#pragma unroll
      for (int nt = 0; nt < 4; ++nt)
        acc[mt][nt] = __builtin_amdgcn_mfma_f32_16x16x32_bf16(af[mt], bf[nt], acc[mt][nt], 0, 0, 0);
  }

  const int er = (lane >> 4) * 4, ec = lane & 15;
#pragma unroll
  for (int mt = 0; mt < 4; ++mt) {
#pragma unroll
    for (int nt = 0; nt < 4; ++nt) {
#pragma unroll
      for (int i = 0; i < 4; ++i) {
        int r = bm * 128 + wr * 64 + mt * 16 + er + i;
        int c = bn * 128 + wc * 64 + nt * 16 + ec;
        float v = acc[mt][nt][i];
        if constexpr (MODE == 0) {
          int bb = r >> 11, t = r & 2047;
          ((unsigned short*)Cout)[((size_t)bb * LPAD + 3 + t) * DIM + c] = f2bf(v + bias[c]);
        } else if constexpr (MODE == 1) {
          if (r < M2 && c < 48) ((float*)Cout)[(size_t)r * 48 + c] = v;
        } else {
          if (r < M2) ((float*)Cout)[(size_t)r * DMODEL + c] = v + bias[c];
        }
      }
    }
  }
}

// ---------------- delta precompute: softplus(d_raw @ W_dt.T + b_dt) -> bf16 ----------------
// grid (2051, 8), block 256: block handles 8 rows x 256 d's.
__global__ __launch_bounds__(256) void delta_kernel(const float* __restrict__ xdbl,
                                                    const float* __restrict__ W_dt,
                                                    const float* __restrict__ b_dt,
                                                    unsigned short* __restrict__ delta) {
  const int d = blockIdx.y * 256 + threadIdx.x;
  const int r0 = blockIdx.x * 8;
  float wv[16];
  const float4* wp = (const float4*)(W_dt + (size_t)d * 16);
#pragma unroll
  for (int q = 0; q < 4; ++q) {
    float4 t = wp[q];
    wv[q * 4 + 0] = t.x; wv[q * 4 + 1] = t.y; wv[q * 4 + 2] = t.z; wv[q * 4 + 3] = t.w;
  }
  const float bd = b_dt[d];
#pragma unroll
  for (int j = 0; j < 8; ++j) {
    const float* dr = xdbl + (size_t)(r0 + j) * 48;   // uniform -> s_load
    float z0 = bd, z1 = 0.f, z2 = 0.f, z3 = 0.f;
#pragma unroll
    for (int n = 0; n < 16; n += 4) {
      z0 = fmaf(dr[n + 0], wv[n + 0], z0);
      z1 = fmaf(dr[n + 1], wv[n + 1], z1);
      z2 = fmaf(dr[n + 2], wv[n + 2], z2);
      z3 = fmaf(dr[n + 3], wv[n + 3], z3);
    }
    float z = (z0 + z1) + (z2 + z3);
    float dl = (z > 20.f) ? z : __logf(1.f + __expf(z));
    delta[(size_t)(r0 + j) * DIM + d] = f2bf(dl);
  }
}

// ---------------- chunked scan, pass 1: per-chunk (sumd, q) ----------------
// 256-thread blocks = 4 independent waves; wave W -> (b, chunk, dgroup).
__global__ __launch_bounds__(256) void scan_pass1(const unsigned short* __restrict__ xc,
                                                  const unsigned short* __restrict__ dl,
                                                  const float* __restrict__ xd,
                                                  float* __restrict__ sdbuf,
                                                  float* __restrict__ qbuf) {
  const int wid = __builtin_amdgcn_readfirstlane((int)(threadIdx.x >> 6));
  const int lane = threadIdx.x & 63;
  const int W = blockIdx.x * 4 + wid;
  const int dg = W & 31;
  const int rest = W >> 5;
  const int c = rest % NCH;
  const int b = rest / NCH;
  const int d = dg * 64 + lane;
  const int t0 = c * CS;
  const int nst = (t0 + CS <= LC) ? CS : (LC - t0);

  float h[16];
#pragma unroll
  for (int n = 0; n < 16; ++n) h[n] = 0.f;
  float sumd = 0.f;

  const size_t row0 = (size_t)b * LC + t0;
  const float* xdb = xd + row0 * 48 + 16;            // B cols (uniform -> s_load)
  const unsigned short* xcp = xc + row0 * DIM + d;
  const unsigned short* dp  = dl + row0 * DIM + d;

  float BA[16], BB[16];
#pragma unroll
  for (int j = 0; j < 16; ++j) BA[j] = xdb[j];
  float d0v = bf2f(dp[0]), x0v = bf2f(xcp[0]);

  auto step = [&](const float (&Bv)[16], float dlt, float xcv) {
    sumd += dlt;
#pragma unroll
    for (int n = 0; n < 16; ++n) {
      float e = __expf(dlt * AeT[n]);
      h[n] = fmaf(h[n], e, xcv * Bv[n]);
    }
  };

  for (int s = 0; s < nst; s += 2) {
    int s1 = (s + 1 < nst) ? s + 1 : s;
#pragma unroll
    for (int j = 0; j < 16; ++j) BB[j] = xdb[(size_t)s1 * 48 + j];
    float d1v = bf2f(dp[(size_t)s1 * DIM]);
    float x1v = bf2f(xcp[(size_t)s1 * DIM]);
    step(BA, d0v, x0v);
    if (s + 1 >= nst) break;
    int s2 = (s + 2 < nst) ? s + 2 : s + 1;
#pragma unroll
    for (int j = 0; j < 16; ++j) BA[j] = xdb[(size_t)s2 * 48 + j];
    d0v = bf2f(dp[(size_t)s2 * DIM]);
    x0v = bf2f(xcp[(size_t)s2 * DIM]);
    step(BB, d1v, x1v);
  }

  sdbuf[((size_t)(b * NCH + c) << 11) + d] = sumd;
  const size_t base = ((size_t)(b * NCH + c) * 16) * 2048 + d;
#pragma unroll
  for (int n = 0; n < 16; ++n) qbuf[base + ((size_t)n << 11)] = h[n];
}

// ---------------- boundary scan: h across chunks; writes h_init over q ----------------
__global__ __launch_bounds__(64) void scan_boundary(const float* __restrict__ sdbuf,
                                                    float* __restrict__ qbuf) {
  const int d = blockIdx.x * 64 + threadIdx.x;
  const int b = blockIdx.y;
  float h[16];
#pragma unroll
  for (int n = 0; n < 16; ++n) h[n] = 0.f;
  for (int c = 0; c < NCH; ++c) {
    const float sd = sdbuf[((size_t)(b * NCH + c) << 11) + d];
    const size_t base = ((size_t)(b * NCH + c) * 16) * 2048 + d;
    float qv[16];
#pragma unroll
    for (int n = 0; n < 16; ++n) qv[n] = qbuf[base + ((size_t)n << 11)];
#pragma unroll
    for (int n = 0; n < 16; ++n) {
      float Pv = __expf(sd * AeT[n]);
      qbuf[base + ((size_t)n << 11)] = h[n];       // h at chunk start
      h[n] = fmaf(Pv, h[n], qv[n]);
    }
  }
}

// ---------------- chunked scan, pass 2: recompute with h_init, emit y ----------------
// NOTE: y aliases dl (in-place, same [r][d] layout); per-element load precedes store
// within the owning thread, and no two threads touch the same element.
__global__ __launch_bounds__(256) void scan_pass2(const unsigned short* __restrict__ xc,
                                                  const unsigned short* __restrict__ dl,
                                                  const float* __restrict__ xd,
                                                  const float* __restrict__ hinit,
                                                  unsigned short* __restrict__ y) {
  const int wid = __builtin_amdgcn_readfirstlane((int)(threadIdx.x >> 6));
  const int lane = threadIdx.x & 63;
  const int W = blockIdx.x * 4 + wid;
  const int dg = W & 31;
  const int rest = W >> 5;
  const int c = rest % NCH;
  const int b = rest / NCH;
  const int d = dg * 64 + lane;
  const int t0 = c * CS;
  const int nst = (t0 + CS <= LC) ? CS : (LC - t0);

  const size_t base = ((size_t)(b * NCH + c) * 16) * 2048 + d;
  float h[16];
#pragma unroll
  for (int n = 0; n < 16; ++n) h[n] = hinit[base + ((size_t)n << 11)];

  const size_t row0 = (size_t)b * LC + t0;
  const float* xdb = xd + row0 * 48 + 16;            // B at [j], C at [16+j]
  const unsigned short* xcp = xc + row0 * DIM + d;
  const unsigned short* dp  = dl + row0 * DIM + d;
  unsigned short* yp = y + row0 * DIM + d;

  float BA[16], CA[16], BB[16], CB[16];
#pragma unroll
  for (int j = 0; j < 16; ++j) { BA[j] = xdb[j]; CA[j] = xdb[16 + j]; }
  float d0v = bf2f(dp[0]), x0v = bf2f(xcp[0]);

  auto step = [&](const float (&Bv)[16], const float (&Cv)[16], float dlt, float xcv, int s) {
    float y0 = 0.f, y1 = 0.f, y2 = 0.f, y3 = 0.f;
#pragma unroll
    for (int n = 0; n < 16; n += 4) {
      float e0 = __expf(dlt * AeT[n + 0]);
      float e1 = __expf(dlt * AeT[n + 1]);
      float e2 = __expf(dlt * AeT[n + 2]);
      float e3 = __expf(dlt * AeT[n + 3]);
      h[n + 0] = fmaf(h[n + 0], e0, xcv * Bv[n + 0]);
      h[n + 1] = fmaf(h[n + 1], e1, xcv * Bv[n + 1]);
      h[n + 2] = fmaf(h[n + 2], e2, xcv * Bv[n + 2]);
      h[n + 3] = fmaf(h[n + 3], e3, xcv * Bv[n + 3]);
      y0 = fmaf(h[n + 0], Cv[n + 0], y0);
      y1 = fmaf(h[n + 1], Cv[n + 1], y1);
      y2 = fmaf(h[n + 2], Cv[n + 2], y2);
      y3 = fmaf(h[n + 3], Cv[n + 3], y3);
    }
    yp[(size_t)s * DIM] = f2bf((y0 + y1) + (y2 + y3));
  };

  for (int s = 0; s < nst; s += 2) {
    int s1 = (s + 1 < nst) ? s + 1 : s;
#pragma unroll
    for (int j = 0; j < 16; ++j) { BB[j] = xdb[(size_t)s1 * 48 + j]; CB[j] = xdb[(size_t)s1 * 48 + 16 + j]; }
    float d1v = bf2f(dp[(size_t)s1 * DIM]);
    float x1v = bf2f(xcp[(size_t)s1 * DIM]);
    step(BA, CA, d0v, x0v, s);
    if (s + 1 >= nst) break;
    int s2 = (s + 2 < nst) ? s + 2 : s + 1;
#pragma unroll
    for (int j = 0; j < 16; ++j) { BA[j] = xdb[(size_t)s2 * 48 + j]; CA[j] = xdb[(size_t)s2 * 48 + 16 + j]; }
    d0v = bf2f(dp[(size_t)s2 * DIM]);
    x0v = bf2f(xcp[(size_t)s2 * DIM]);
    step(BB, CB, d1v, x1v, s + 1);
  }
}

// ---------------- launch ----------------
extern "C" void kernel_launch(void* const* d_in, const int* in_sizes, int n_in,
                              void* d_out, int out_size, void* d_ws, size_t ws_size,
                              hipStream_t stream) {
  const float* x      = (const float*)d_in[0];
  const float* W_in   = (const float*)d_in[1];
  const float* b_in   = (const float*)d_in[2];
  const float* conv_w = (const float*)d_in[3];
  const float* conv_b = (const float*)d_in[4];
  const float* W_x    = (const float*)d_in[5];
  const float* W_dt   = (const float*)d_in[6];
  const float* b_dt   = (const float*)d_in[7];
  const float* W_out  = (const float*)d_in[8];
  const float* b_out  = (const float*)d_in[9];

  char* w = (char*)d_ws;
  // region 0 (67.63 MB): xp (LPAD layout) -> delta [M2P][DIM] -> y (in-place over delta)
  unsigned short* xp    = (unsigned short*)w;
  unsigned short* delta = (unsigned short*)w;
  unsigned short* ybuf  = (unsigned short*)w;
  size_t off = (size_t)M2P * DIM * 2;                                  // 67,633,152
  unsigned short* xcb  = (unsigned short*)(w + off); off += (size_t)M2P * DIM * 2;
  size_t xA_off = off;                                                 // 135,266,304
  unsigned short* xA   = (unsigned short*)(w + off); off += (size_t)16384 * 1024 * 2;
  unsigned short* wInB = (unsigned short*)(w + off); off += (size_t)2048 * 1024 * 2;
  unsigned short* wOutB= (unsigned short*)(w + off); off += (size_t)1024 * 2048 * 2;
  unsigned short* wXB  = (unsigned short*)(w + off); off += (size_t)128 * 2048 * 2;
  float* xdbl          = (float*)(w + off);          off += (size_t)M2 * 48 * 4;
  // sdbuf (2.16 MB) + qbuf (34.6 MB) reuse xA+wInB region (dead after gemm1):
  // 2,162,688 + 34,603,008 = 36.77 MB < 37.75 MB available.
  float* sdbuf         = (float*)(w + xA_off);
  float* qbuf          = (float*)(w + xA_off + (size_t)B8 * NCH * 2048 * 4);
  (void)ws_size; (void)in_sizes; (void)n_in; (void)out_size;

  cvt_f32_bf16<<<8192, 256, 0, stream>>>(x, xA, 2097152);
  cvt_f32_bf16<<<1024, 256, 0, stream>>>(W_in, wInB, 262144);
  cvt_f32_bf16<<<1024, 256, 0, stream>>>(W_out, wOutB, 262144);
  cvt_f32_bf16<<<48,   256, 0, stream>>>(W_x, wXB, 12288);
  zero_pads<<<48, 256, 0, stream>>>(xp);

  gemm_bt<0><<<dim3(128, 16), 256, 0, stream>>>(xA, wInB, b_in, xp, 1024);
  conv_kernel<<<dim3(LC, B8), 256, 0, stream>>>(xp, conv_w, conv_b, xcb);
  gemm_bt<1><<<dim3(129, 1), 256, 0, stream>>>(xcb, wXB, nullptr, xdbl, 2048);
  delta_kernel<<<dim3(2051, 8), 256, 0, stream>>>(xdbl, W_dt, b_dt, delta);

  scan_pass1<<<2112, 256, 0, stream>>>(xcb, delta, xdbl, sdbuf, qbuf);
  scan_boundary<<<dim3(32, B8), 64, 0, stream>>>(sdbuf, qbuf);
  scan_pass2<<<2112, 256, 0, stream>>>(xcb, delta, xdbl, qbuf, ybuf);

  gemm_bt<2><<<dim3(129, 8), 256, 0, stream>>>(ybuf, wOutB, b_out, (float*)d_out, 2048);
}

// Round 4
// 658.077 us; speedup vs baseline: 2.6530x; 1.0469x over previous
//
#include <hip/hip_runtime.h>
#include <cstdint>
#include <cstddef>

#define B8 8
#define LSEQ 2048
#define LC 2051
#define DMODEL 1024
#define DIM 2048
#define LPAD 2054           // 3 + 2048 + 3 zero-padded rows per batch
#define M2 16408            // B8*LC valid rows
#define M2P 16512           // padded to multiple of 128
#define CS 64               // scan chunk size
#define NCH 33              // ceil(2051/64)

typedef __attribute__((ext_vector_type(8))) short short8;
typedef __attribute__((ext_vector_type(4))) float floatx4;

// A_n = -exp(-n/3), n=0..15 (compile-time literals)
__device__ __constant__ float AeT[16] = {
  -1.0f,          -0.71653131f, -0.51341712f, -0.36787944f,
  -0.26359714f,   -0.18887560f, -0.13533528f, -0.09697208f,
  -0.06948345f,   -0.04978707f, -0.03567399f, -0.02556154f,
  -0.01831564f,   -0.01312373f, -0.00940356f, -0.00673795f};

__device__ __forceinline__ float bf2f(unsigned short h) {
  union { unsigned int u; float f; } v; v.u = ((unsigned int)h) << 16; return v.f;
}
__device__ __forceinline__ unsigned short f2bf(float f) {
  union { float f; unsigned int u; } v; v.f = f;
  unsigned int r = (v.u + 0x7FFFu + ((v.u >> 16) & 1u)) >> 16;
  return (unsigned short)r;
}

// ---------------- fp32 -> bf16 convert (8 elems/thread) ----------------
__global__ __launch_bounds__(256) void cvt_f32_bf16(const float* __restrict__ in,
                                                    unsigned short* __restrict__ out,
                                                    int n8) {
  int i = blockIdx.x * 256 + threadIdx.x;
  if (i >= n8) return;
  const float4* p = (const float4*)in + (size_t)i * 2;
  float4 a = p[0], b = p[1];
  uint4 o;
  o.x = (unsigned)f2bf(a.x) | ((unsigned)f2bf(a.y) << 16);
  o.y = (unsigned)f2bf(a.z) | ((unsigned)f2bf(a.w) << 16);
  o.z = (unsigned)f2bf(b.x) | ((unsigned)f2bf(b.y) << 16);
  o.w = (unsigned)f2bf(b.z) | ((unsigned)f2bf(b.w) << 16);
  *((uint4*)out + i) = o;
}

// ---------------- zero the 6 pad rows per batch of xp ----------------
__global__ __launch_bounds__(256) void zero_pads(unsigned short* __restrict__ xp) {
  int i = blockIdx.x * 256 + threadIdx.x;      // 0..12287
  int b = i / 1536;
  int r6 = (i % 1536) / 256;
  int dd = (i % 256) * 8;
  int row = (r6 < 3) ? r6 : (2048 + r6);       // 0,1,2,2051,2052,2053
  uint4 z = make_uint4(0, 0, 0, 0);
  *(uint4*)(xp + ((size_t)b * LPAD + row) * DIM + dd) = z;
}

// ---------------- depthwise conv1d: xp(padded bf16) -> xc bf16 ----------------
__global__ __launch_bounds__(256) void conv_kernel(const unsigned short* __restrict__ xp,
                                                   const float* __restrict__ conv_w,
                                                   const float* __restrict__ conv_b,
                                                   unsigned short* __restrict__ xc) {
  const int tc = blockIdx.x, b = blockIdx.y;
  const int d0 = threadIdx.x * 8;
  const unsigned short* base = xp + ((size_t)b * LPAD + tc) * DIM + d0;

  float4 cw[8];
#pragma unroll
  for (int j = 0; j < 8; ++j) cw[j] = *(const float4*)(conv_w + (size_t)(d0 + j) * 4);

  float acc[8];
  const float4* cb4 = (const float4*)(conv_b + d0);
  float4 cb0 = cb4[0], cb1 = cb4[1];
  acc[0] = cb0.x; acc[1] = cb0.y; acc[2] = cb0.z; acc[3] = cb0.w;
  acc[4] = cb1.x; acc[5] = cb1.y; acc[6] = cb1.z; acc[7] = cb1.w;

#pragma unroll
  for (int k = 0; k < 4; ++k) {
    uint4 v = *(const uint4*)(base + (size_t)k * DIM);
    unsigned short e[8];
    e[0] = v.x & 0xffff; e[1] = v.x >> 16; e[2] = v.y & 0xffff; e[3] = v.y >> 16;
    e[4] = v.z & 0xffff; e[5] = v.z >> 16; e[6] = v.w & 0xffff; e[7] = v.w >> 16;
#pragma unroll
    for (int j = 0; j < 8; ++j)
      acc[j] = fmaf(bf2f(e[j]), ((const float*)&cw[j])[k], acc[j]);
  }
  uint4 o;
  o.x = (unsigned)f2bf(acc[0]) | ((unsigned)f2bf(acc[1]) << 16);
  o.y = (unsigned)f2bf(acc[2]) | ((unsigned)f2bf(acc[3]) << 16);
  o.z = (unsigned)f2bf(acc[4]) | ((unsigned)f2bf(acc[5]) << 16);
  o.w = (unsigned)f2bf(acc[6]) | ((unsigned)f2bf(acc[7]) << 16);
  *(uint4*)(xc + ((size_t)b * LC + tc) * DIM + d0) = o;
}

// ---------------- bf16 MFMA GEMM: C = A(MxK) @ B(NxK)^T, m97 structure ----------------
#define GAS(p) ((const __attribute__((address_space(1))) void*)(p))
#define LAS(p) ((__attribute__((address_space(3))) void*)(p))

// 1D grid, XCD-banded bn-major remap: xcd = gid&7 owns bm band [xcd*LX, xcd*LX+LX);
// within a band, bmL cycles fastest so the A-band stays hot in the XCD's private L2
// across the bn sweep. Grid size = 8*LX*NBN; blocks with bm >= NBM exit early.
// MODE 0: gemm1 -> xp padded bf16, +b_in      (M=16384, N=2048)
// MODE 1: xdbl  -> fp32 [M2][48], cols<48     (M=16512, N=128)
// MODE 2: out   -> fp32 [M2][1024], +b_out    (M=16512, N=1024)
template <int MODE, int NBM, int NBN, int LX>
__global__ __launch_bounds__(256) void gemm_bt(const unsigned short* __restrict__ A,
                                               const unsigned short* __restrict__ Bw,
                                               const float* __restrict__ bias,
                                               void* __restrict__ Cout, int K) {
  const int gid = blockIdx.x;
  const int xcd = gid & 7;
  const int j = gid >> 3;
  const int bmL = j % LX;
  const int bn = j / LX;
  const int bm = xcd * LX + bmL;
  if (bm >= NBM) return;

  __shared__ __align__(16) short As[128 * 32];
  __shared__ __align__(16) short Bs[128 * 32];
  const int tid = threadIdx.x;
  const int lane = tid & 63, wave = tid >> 6;
  const int wr = wave >> 1, wc = wave & 1;

  floatx4 acc[4][4];
#pragma unroll
  for (int i = 0; i < 4; ++i)
#pragma unroll
    for (int j2 = 0; j2 < 4; ++j2) acc[i][j2] = (floatx4){0.f, 0.f, 0.f, 0.f};

  const int sr = tid >> 2;             // staging row 0..63
  const int sc = (tid & 3) * 8;        // staging col (elems)
  const unsigned short* Ab = A + (size_t)(bm * 128 + sr) * K + sc;
  const unsigned short* Bb = Bw + (size_t)(bn * 128 + sr) * K + sc;
  const size_t rowK64 = (size_t)64 * K;

  const int fr = lane & 15;
  const int fk = (lane >> 4) * 8;
  const int aoff0 = (wr * 64 + fr) * 32 + fk;
  const int boff0 = (wc * 64 + fr) * 32 + fk;

  for (int k0 = 0; k0 < K; k0 += 32) {
    __syncthreads();  // previous compute done before overwrite
    __builtin_amdgcn_global_load_lds(GAS(Ab + k0),          LAS(As + tid * 8), 16, 0, 0);
    __builtin_amdgcn_global_load_lds(GAS(Ab + rowK64 + k0), LAS(As + 2048 + tid * 8), 16, 0, 0);
    __builtin_amdgcn_global_load_lds(GAS(Bb + k0),          LAS(Bs + tid * 8), 16, 0, 0);
    __builtin_amdgcn_global_load_lds(GAS(Bb + rowK64 + k0), LAS(Bs + 2048 + tid * 8), 16, 0, 0);
    __syncthreads();  // drains vmcnt -> LDS ready

    short8 af[4], bf[4];
#pragma unroll
    for (int mt = 0; mt < 4; ++mt) af[mt] = *(const short8*)&As[aoff0 + mt * 16 * 32];
#pragma unroll
    for (int nt = 0; nt < 4; ++nt) bf[nt] = *(const short8*)&Bs[boff0 + nt * 16 * 32];
#pragma unroll
    for (int mt = 0; mt < 4; ++mt)
#pragma unroll
      for (int nt = 0; nt < 4; ++nt)
        acc[mt][nt] = __builtin_amdgcn_mfma_f32_16x16x32_bf16(af[mt], bf[nt], acc[mt][nt], 0, 0, 0);
  }

  const int er = (lane >> 4) * 4, ec = lane & 15;
#pragma unroll
  for (int mt = 0; mt < 4; ++mt) {
#pragma unroll
    for (int nt = 0; nt < 4; ++nt) {
#pragma unroll
      for (int i = 0; i < 4; ++i) {
        int r = bm * 128 + wr * 64 + mt * 16 + er + i;
        int c = bn * 128 + wc * 64 + nt * 16 + ec;
        float v = acc[mt][nt][i];
        if constexpr (MODE == 0) {
          int bb = r >> 11, t = r & 2047;
          ((unsigned short*)Cout)[((size_t)bb * LPAD + 3 + t) * DIM + c] = f2bf(v + bias[c]);
        } else if constexpr (MODE == 1) {
          if (r < M2 && c < 48) ((float*)Cout)[(size_t)r * 48 + c] = v;
        } else {
          if (r < M2) ((float*)Cout)[(size_t)r * DMODEL + c] = v + bias[c];
        }
      }
    }
  }
}

// ---------------- delta precompute: softplus(d_raw @ W_dt.T + b_dt) -> bf16 ----------------
__global__ __launch_bounds__(256) void delta_kernel(const float* __restrict__ xdbl,
                                                    const float* __restrict__ W_dt,
                                                    const float* __restrict__ b_dt,
                                                    unsigned short* __restrict__ delta) {
  const int d = blockIdx.y * 256 + threadIdx.x;
  const int r0 = blockIdx.x * 8;
  float wv[16];
  const float4* wp = (const float4*)(W_dt + (size_t)d * 16);
#pragma unroll
  for (int q = 0; q < 4; ++q) {
    float4 t = wp[q];
    wv[q * 4 + 0] = t.x; wv[q * 4 + 1] = t.y; wv[q * 4 + 2] = t.z; wv[q * 4 + 3] = t.w;
  }
  const float bd = b_dt[d];
#pragma unroll
  for (int j = 0; j < 8; ++j) {
    const float* dr = xdbl + (size_t)(r0 + j) * 48;   // uniform -> s_load
    float z0 = bd, z1 = 0.f, z2 = 0.f, z3 = 0.f;
#pragma unroll
    for (int n = 0; n < 16; n += 4) {
      z0 = fmaf(dr[n + 0], wv[n + 0], z0);
      z1 = fmaf(dr[n + 1], wv[n + 1], z1);
      z2 = fmaf(dr[n + 2], wv[n + 2], z2);
      z3 = fmaf(dr[n + 3], wv[n + 3], z3);
    }
    float z = (z0 + z1) + (z2 + z3);
    float dl = (z > 20.f) ? z : __logf(1.f + __expf(z));
    delta[(size_t)(r0 + j) * DIM + d] = f2bf(dl);
  }
}

// ---------------- chunked scan, pass 1: per-chunk (sumd, q) ----------------
__global__ __launch_bounds__(256) void scan_pass1(const unsigned short* __restrict__ xc,
                                                  const unsigned short* __restrict__ dl,
                                                  const float* __restrict__ xd,
                                                  float* __restrict__ sdbuf,
                                                  float* __restrict__ qbuf) {
  const int wid = __builtin_amdgcn_readfirstlane((int)(threadIdx.x >> 6));
  const int lane = threadIdx.x & 63;
  const int W = blockIdx.x * 4 + wid;
  const int dg = W & 31;
  const int rest = W >> 5;
  const int c = rest % NCH;
  const int b = rest / NCH;
  const int d = dg * 64 + lane;
  const int t0 = c * CS;
  const int nst = (t0 + CS <= LC) ? CS : (LC - t0);

  float h[16];
#pragma unroll
  for (int n = 0; n < 16; ++n) h[n] = 0.f;
  float sumd = 0.f;

  const size_t row0 = (size_t)b * LC + t0;
  const float* xdb = xd + row0 * 48 + 16;            // B cols (uniform -> s_load)
  const unsigned short* xcp = xc + row0 * DIM + d;
  const unsigned short* dp  = dl + row0 * DIM + d;

  float BA[16], BB[16];
#pragma unroll
  for (int j = 0; j < 16; ++j) BA[j] = xdb[j];
  float d0v = bf2f(dp[0]), x0v = bf2f(xcp[0]);

  auto step = [&](const float (&Bv)[16], float dlt, float xcv) {
    sumd += dlt;
#pragma unroll
    for (int n = 0; n < 16; ++n) {
      float e = __expf(dlt * AeT[n]);
      h[n] = fmaf(h[n], e, xcv * Bv[n]);
    }
  };

  for (int s = 0; s < nst; s += 2) {
    int s1 = (s + 1 < nst) ? s + 1 : s;
#pragma unroll
    for (int j = 0; j < 16; ++j) BB[j] = xdb[(size_t)s1 * 48 + j];
    float d1v = bf2f(dp[(size_t)s1 * DIM]);
    float x1v = bf2f(xcp[(size_t)s1 * DIM]);
    step(BA, d0v, x0v);
    if (s + 1 >= nst) break;
    int s2 = (s + 2 < nst) ? s + 2 : s + 1;
#pragma unroll
    for (int j = 0; j < 16; ++j) BA[j] = xdb[(size_t)s2 * 48 + j];
    d0v = bf2f(dp[(size_t)s2 * DIM]);
    x0v = bf2f(xcp[(size_t)s2 * DIM]);
    step(BB, d1v, x1v);
  }

  sdbuf[((size_t)(b * NCH + c) << 11) + d] = sumd;
  const size_t base = ((size_t)(b * NCH + c) * 16) * 2048 + d;
#pragma unroll
  for (int n = 0; n < 16; ++n) qbuf[base + ((size_t)n << 11)] = h[n];
}

// ---------------- boundary scan: h across chunks; writes h_init over q ----------------
__global__ __launch_bounds__(64) void scan_boundary(const float* __restrict__ sdbuf,
                                                    float* __restrict__ qbuf) {
  const int d = blockIdx.x * 64 + threadIdx.x;
  const int b = blockIdx.y;
  float h[16];
#pragma unroll
  for (int n = 0; n < 16; ++n) h[n] = 0.f;
  for (int c = 0; c < NCH; ++c) {
    const float sd = sdbuf[((size_t)(b * NCH + c) << 11) + d];
    const size_t base = ((size_t)(b * NCH + c) * 16) * 2048 + d;
    float qv[16];
#pragma unroll
    for (int n = 0; n < 16; ++n) qv[n] = qbuf[base + ((size_t)n << 11)];
#pragma unroll
    for (int n = 0; n < 16; ++n) {
      float Pv = __expf(sd * AeT[n]);
      qbuf[base + ((size_t)n << 11)] = h[n];       // h at chunk start
      h[n] = fmaf(Pv, h[n], qv[n]);
    }
  }
}

// ---------------- chunked scan, pass 2: recompute with h_init, emit y ----------------
// NOTE: y aliases dl (in-place, same [r][d] layout); per-element load precedes store
// within the owning thread, and no two threads touch the same element.
__global__ __launch_bounds__(256) void scan_pass2(const unsigned short* __restrict__ xc,
                                                  const unsigned short* __restrict__ dl,
                                                  const float* __restrict__ xd,
                                                  const float* __restrict__ hinit,
                                                  unsigned short* __restrict__ y) {
  const int wid = __builtin_amdgcn_readfirstlane((int)(threadIdx.x >> 6));
  const int lane = threadIdx.x & 63;
  const int W = blockIdx.x * 4 + wid;
  const int dg = W & 31;
  const int rest = W >> 5;
  const int c = rest % NCH;
  const int b = rest / NCH;
  const int d = dg * 64 + lane;
  const int t0 = c * CS;
  const int nst = (t0 + CS <= LC) ? CS : (LC - t0);

  const size_t base = ((size_t)(b * NCH + c) * 16) * 2048 + d;
  float h[16];
#pragma unroll
  for (int n = 0; n < 16; ++n) h[n] = hinit[base + ((size_t)n << 11)];

  const size_t row0 = (size_t)b * LC + t0;
  const float* xdb = xd + row0 * 48 + 16;            // B at [j], C at [16+j]
  const unsigned short* xcp = xc + row0 * DIM + d;
  const unsigned short* dp  = dl + row0 * DIM + d;
  unsigned short* yp = y + row0 * DIM + d;

  float BA[16], CA[16], BB[16], CB[16];
#pragma unroll
  for (int j = 0; j < 16; ++j) { BA[j] = xdb[j]; CA[j] = xdb[16 + j]; }
  float d0v = bf2f(dp[0]), x0v = bf2f(xcp[0]);

  auto step = [&](const float (&Bv)[16], const float (&Cv)[16], float dlt, float xcv, int s) {
    float y0 = 0.f, y1 = 0.f, y2 = 0.f, y3 = 0.f;
#pragma unroll
    for (int n = 0; n < 16; n += 4) {
      float e0 = __expf(dlt * AeT[n + 0]);
      float e1 = __expf(dlt * AeT[n + 1]);
      float e2 = __expf(dlt * AeT[n + 2]);
      float e3 = __expf(dlt * AeT[n + 3]);
      h[n + 0] = fmaf(h[n + 0], e0, xcv * Bv[n + 0]);
      h[n + 1] = fmaf(h[n + 1], e1, xcv * Bv[n + 1]);
      h[n + 2] = fmaf(h[n + 2], e2, xcv * Bv[n + 2]);
      h[n + 3] = fmaf(h[n + 3], e3, xcv * Bv[n + 3]);
      y0 = fmaf(h[n + 0], Cv[n + 0], y0);
      y1 = fmaf(h[n + 1], Cv[n + 1], y1);
      y2 = fmaf(h[n + 2], Cv[n + 2], y2);
      y3 = fmaf(h[n + 3], Cv[n + 3], y3);
    }
    yp[(size_t)s * DIM] = f2bf((y0 + y1) + (y2 + y3));
  };

  for (int s = 0; s < nst; s += 2) {
    int s1 = (s + 1 < nst) ? s + 1 : s;
#pragma unroll
    for (int j = 0; j < 16; ++j) { BB[j] = xdb[(size_t)s1 * 48 + j]; CB[j] = xdb[(size_t)s1 * 48 + 16 + j]; }
    float d1v = bf2f(dp[(size_t)s1 * DIM]);
    float x1v = bf2f(xcp[(size_t)s1 * DIM]);
    step(BA, CA, d0v, x0v, s);
    if (s + 1 >= nst) break;
    int s2 = (s + 2 < nst) ? s + 2 : s + 1;
#pragma unroll
    for (int j = 0; j < 16; ++j) { BA[j] = xdb[(size_t)s2 * 48 + j]; CA[j] = xdb[(size_t)s2 * 48 + 16 + j]; }
    d0v = bf2f(dp[(size_t)s2 * DIM]);
    x0v = bf2f(xcp[(size_t)s2 * DIM]);
    step(BB, CB, d1v, x1v, s + 1);
  }
}

// ---------------- launch ----------------
extern "C" void kernel_launch(void* const* d_in, const int* in_sizes, int n_in,
                              void* d_out, int out_size, void* d_ws, size_t ws_size,
                              hipStream_t stream) {
  const float* x      = (const float*)d_in[0];
  const float* W_in   = (const float*)d_in[1];
  const float* b_in   = (const float*)d_in[2];
  const float* conv_w = (const float*)d_in[3];
  const float* conv_b = (const float*)d_in[4];
  const float* W_x    = (const float*)d_in[5];
  const float* W_dt   = (const float*)d_in[6];
  const float* b_dt   = (const float*)d_in[7];
  const float* W_out  = (const float*)d_in[8];
  const float* b_out  = (const float*)d_in[9];

  char* w = (char*)d_ws;
  // region 0 (67.63 MB): xp (LPAD layout) -> delta [M2P][DIM] -> y (in-place over delta)
  unsigned short* xp    = (unsigned short*)w;
  unsigned short* delta = (unsigned short*)w;
  unsigned short* ybuf  = (unsigned short*)w;
  size_t off = (size_t)M2P * DIM * 2;                                  // 67,633,152
  unsigned short* xcb  = (unsigned short*)(w + off); off += (size_t)M2P * DIM * 2;
  size_t xA_off = off;                                                 // 135,266,304
  unsigned short* xA   = (unsigned short*)(w + off); off += (size_t)16384 * 1024 * 2;
  unsigned short* wInB = (unsigned short*)(w + off); off += (size_t)2048 * 1024 * 2;
  unsigned short* wOutB= (unsigned short*)(w + off); off += (size_t)1024 * 2048 * 2;
  unsigned short* wXB  = (unsigned short*)(w + off); off += (size_t)128 * 2048 * 2;
  float* xdbl          = (float*)(w + off);          off += (size_t)M2 * 48 * 4;
  // sdbuf (2.16 MB) + qbuf (34.6 MB) reuse xA+wInB region (dead after gemm1):
  float* sdbuf         = (float*)(w + xA_off);
  float* qbuf          = (float*)(w + xA_off + (size_t)B8 * NCH * 2048 * 4);
  (void)ws_size; (void)in_sizes; (void)n_in; (void)out_size;

  cvt_f32_bf16<<<8192, 256, 0, stream>>>(x, xA, 2097152);
  cvt_f32_bf16<<<1024, 256, 0, stream>>>(W_in, wInB, 262144);
  cvt_f32_bf16<<<1024, 256, 0, stream>>>(W_out, wOutB, 262144);
  cvt_f32_bf16<<<48,   256, 0, stream>>>(W_x, wXB, 12288);
  zero_pads<<<48, 256, 0, stream>>>(xp);

  // grid = 8 * LX * NBN (1D, XCD-banded remap inside)
  gemm_bt<0, 128, 16, 16><<<2048, 256, 0, stream>>>(xA, wInB, b_in, xp, 1024);
  conv_kernel<<<dim3(LC, B8), 256, 0, stream>>>(xp, conv_w, conv_b, xcb);
  gemm_bt<1, 129, 1, 17><<<136, 256, 0, stream>>>(xcb, wXB, nullptr, xdbl, 2048);
  delta_kernel<<<dim3(2051, 8), 256, 0, stream>>>(xdbl, W_dt, b_dt, delta);

  scan_pass1<<<2112, 256, 0, stream>>>(xcb, delta, xdbl, sdbuf, qbuf);
  scan_boundary<<<dim3(32, B8), 64, 0, stream>>>(sdbuf, qbuf);
  scan_pass2<<<2112, 256, 0, stream>>>(xcb, delta, xdbl, qbuf, ybuf);

  gemm_bt<2, 129, 8, 17><<<1088, 256, 0, stream>>>(ybuf, wOutB, b_out, (float*)d_out, 2048);
}

// Round 5
// 614.266 us; speedup vs baseline: 2.8422x; 1.0713x over previous
//
#include <hip/hip_runtime.h>
#include <cstdint>
#include <cstddef>

#define B8 8
#define LSEQ 2048
#define LC 2051
#define DMODEL 1024
#define DIM 2048
#define LPAD 2054           // 3 + 2048 + 3 zero-padded rows per batch
#define M2 16408            // B8*LC valid rows
#define M2P 16512           // padded to multiple of 128
#define CS 32               // scan chunk size
#define NCH 65              // ceil(2051/32)

typedef __attribute__((ext_vector_type(8))) short short8;
typedef __attribute__((ext_vector_type(4))) float floatx4;
typedef __attribute__((ext_vector_type(2))) float float2v;

// A_n = -exp(-n/3), n=0..15
__device__ __constant__ float AeT[16] = {
  -1.0f,          -0.71653131f, -0.51341712f, -0.36787944f,
  -0.26359714f,   -0.18887560f, -0.13533528f, -0.09697208f,
  -0.06948345f,   -0.04978707f, -0.03567399f, -0.02556154f,
  -0.01831564f,   -0.01312373f, -0.00940356f, -0.00673795f};

#define LOG2E 1.44269504088896f

__device__ __forceinline__ float bf2f(unsigned short h) {
  union { unsigned int u; float f; } v; v.u = ((unsigned int)h) << 16; return v.f;
}
__device__ __forceinline__ unsigned short f2bf(float f) {
  union { float f; unsigned int u; } v; v.f = f;
  unsigned int r = (v.u + 0x7FFFu + ((v.u >> 16) & 1u)) >> 16;
  return (unsigned short)r;
}

// ---- packed fp32 helpers (VOP3P). One scalar operand allowed per instr. ----
__device__ __forceinline__ float2v pk_mul_vv(float2v a, float2v b) {
  float2v d; asm("v_pk_mul_f32 %0, %1, %2" : "=v"(d) : "v"(a), "v"(b)); return d;
}
__device__ __forceinline__ float2v pk_mul_sv(float2v bs, float2v a) {   // bs wave-uniform (SGPR)
  float2v d; asm("v_pk_mul_f32 %0, %1, %2" : "=v"(d) : "s"(bs), "v"(a)); return d;
}
__device__ __forceinline__ float2v pk_fma_vvv(float2v a, float2v b, float2v c) {
  float2v d; asm("v_pk_fma_f32 %0, %1, %2, %3" : "=v"(d) : "v"(a), "v"(b), "v"(c)); return d;
}
__device__ __forceinline__ float2v pk_fma_vsv(float2v a, float2v bs, float2v c) { // bs uniform
  float2v d; asm("v_pk_fma_f32 %0, %1, %2, %3" : "=v"(d) : "v"(a), "s"(bs), "v"(c)); return d;
}
__device__ __forceinline__ float2v pk_add_vv(float2v a, float2v b) {
  float2v d; asm("v_pk_add_f32 %0, %1, %2" : "=v"(d) : "v"(a), "v"(b)); return d;
}
__device__ __forceinline__ float exp2_raw(float x) {   // 2^x
  float d; asm("v_exp_f32 %0, %1" : "=v"(d) : "v"(x)); return d;
}

// ---------------- fp32 -> bf16 convert (8 elems/thread) ----------------
__global__ __launch_bounds__(256) void cvt_f32_bf16(const float* __restrict__ in,
                                                    unsigned short* __restrict__ out,
                                                    int n8) {
  int i = blockIdx.x * 256 + threadIdx.x;
  if (i >= n8) return;
  const float4* p = (const float4*)in + (size_t)i * 2;
  float4 a = p[0], b = p[1];
  uint4 o;
  o.x = (unsigned)f2bf(a.x) | ((unsigned)f2bf(a.y) << 16);
  o.y = (unsigned)f2bf(a.z) | ((unsigned)f2bf(a.w) << 16);
  o.z = (unsigned)f2bf(b.x) | ((unsigned)f2bf(b.y) << 16);
  o.w = (unsigned)f2bf(b.z) | ((unsigned)f2bf(b.w) << 16);
  *((uint4*)out + i) = o;
}

// ---------------- zero the 6 pad rows per batch of xp ----------------
__global__ __launch_bounds__(256) void zero_pads(unsigned short* __restrict__ xp) {
  int i = blockIdx.x * 256 + threadIdx.x;      // 0..12287
  int b = i / 1536;
  int r6 = (i % 1536) / 256;
  int dd = (i % 256) * 8;
  int row = (r6 < 3) ? r6 : (2048 + r6);       // 0,1,2,2051,2052,2053
  uint4 z = make_uint4(0, 0, 0, 0);
  *(uint4*)(xp + ((size_t)b * LPAD + row) * DIM + dd) = z;
}

// ---------------- depthwise conv1d: xp(padded bf16) -> xc bf16 ----------------
__global__ __launch_bounds__(256) void conv_kernel(const unsigned short* __restrict__ xp,
                                                   const float* __restrict__ conv_w,
                                                   const float* __restrict__ conv_b,
                                                   unsigned short* __restrict__ xc) {
  const int tc = blockIdx.x, b = blockIdx.y;
  const int d0 = threadIdx.x * 8;
  const unsigned short* base = xp + ((size_t)b * LPAD + tc) * DIM + d0;

  float4 cw[8];
#pragma unroll
  for (int j = 0; j < 8; ++j) cw[j] = *(const float4*)(conv_w + (size_t)(d0 + j) * 4);

  float acc[8];
  const float4* cb4 = (const float4*)(conv_b + d0);
  float4 cb0 = cb4[0], cb1 = cb4[1];
  acc[0] = cb0.x; acc[1] = cb0.y; acc[2] = cb0.z; acc[3] = cb0.w;
  acc[4] = cb1.x; acc[5] = cb1.y; acc[6] = cb1.z; acc[7] = cb1.w;

#pragma unroll
  for (int k = 0; k < 4; ++k) {
    uint4 v = *(const uint4*)(base + (size_t)k * DIM);
    unsigned short e[8];
    e[0] = v.x & 0xffff; e[1] = v.x >> 16; e[2] = v.y & 0xffff; e[3] = v.y >> 16;
    e[4] = v.z & 0xffff; e[5] = v.z >> 16; e[6] = v.w & 0xffff; e[7] = v.w >> 16;
#pragma unroll
    for (int j = 0; j < 8; ++j)
      acc[j] = fmaf(bf2f(e[j]), ((const float*)&cw[j])[k], acc[j]);
  }
  uint4 o;
  o.x = (unsigned)f2bf(acc[0]) | ((unsigned)f2bf(acc[1]) << 16);
  o.y = (unsigned)f2bf(acc[2]) | ((unsigned)f2bf(acc[3]) << 16);
  o.z = (unsigned)f2bf(acc[4]) | ((unsigned)f2bf(acc[5]) << 16);
  o.w = (unsigned)f2bf(acc[6]) | ((unsigned)f2bf(acc[7]) << 16);
  *(uint4*)(xc + ((size_t)b * LC + tc) * DIM + d0) = o;
}

// ---------------- bf16 MFMA GEMM: C = A(MxK) @ B(NxK)^T, m97 structure ----------------
#define GAS(p) ((const __attribute__((address_space(1))) void*)(p))
#define LAS(p) ((__attribute__((address_space(3))) void*)(p))

template <int MODE, int NBM, int NBN, int LX>
__global__ __launch_bounds__(256) void gemm_bt(const unsigned short* __restrict__ A,
                                               const unsigned short* __restrict__ Bw,
                                               const float* __restrict__ bias,
                                               void* __restrict__ Cout, int K) {
  const int gid = blockIdx.x;
  const int xcd = gid & 7;
  const int j = gid >> 3;
  const int bmL = j % LX;
  const int bn = j / LX;
  const int bm = xcd * LX + bmL;
  if (bm >= NBM) return;

  __shared__ __align__(16) short As[128 * 32];
  __shared__ __align__(16) short Bs[128 * 32];
  const int tid = threadIdx.x;
  const int lane = tid & 63, wave = tid >> 6;
  const int wr = wave >> 1, wc = wave & 1;

  floatx4 acc[4][4];
#pragma unroll
  for (int i = 0; i < 4; ++i)
#pragma unroll
    for (int j2 = 0; j2 < 4; ++j2) acc[i][j2] = (floatx4){0.f, 0.f, 0.f, 0.f};

  const int sr = tid >> 2;             // staging row 0..63
  const int sc = (tid & 3) * 8;        // staging col (elems)
  const unsigned short* Ab = A + (size_t)(bm * 128 + sr) * K + sc;
  const unsigned short* Bb = Bw + (size_t)(bn * 128 + sr) * K + sc;
  const size_t rowK64 = (size_t)64 * K;

  const int fr = lane & 15;
  const int fk = (lane >> 4) * 8;
  const int aoff0 = (wr * 64 + fr) * 32 + fk;
  const int boff0 = (wc * 64 + fr) * 32 + fk;

  for (int k0 = 0; k0 < K; k0 += 32) {
    __syncthreads();  // previous compute done before overwrite
    __builtin_amdgcn_global_load_lds(GAS(Ab + k0),          LAS(As + tid * 8), 16, 0, 0);
    __builtin_amdgcn_global_load_lds(GAS(Ab + rowK64 + k0), LAS(As + 2048 + tid * 8), 16, 0, 0);
    __builtin_amdgcn_global_load_lds(GAS(Bb + k0),          LAS(Bs + tid * 8), 16, 0, 0);
    __builtin_amdgcn_global_load_lds(GAS(Bb + rowK64 + k0), LAS(Bs + 2048 + tid * 8), 16, 0, 0);
    __syncthreads();  // drains vmcnt -> LDS ready

    short8 af[4], bf[4];
#pragma unroll
    for (int mt = 0; mt < 4; ++mt) af[mt] = *(const short8*)&As[aoff0 + mt * 16 * 32];
#pragma unroll
    for (int nt = 0; nt < 4; ++nt) bf[nt] = *(const short8*)&Bs[boff0 + nt * 16 * 32];
#pragma unroll
    for (int mt = 0; mt < 4; ++mt)
#pragma unroll
      for (int nt = 0; nt < 4; ++nt)
        acc[mt][nt] = __builtin_amdgcn_mfma_f32_16x16x32_bf16(af[mt], bf[nt], acc[mt][nt], 0, 0, 0);
  }

  const int er = (lane >> 4) * 4, ec = lane & 15;
#pragma unroll
  for (int mt = 0; mt < 4; ++mt) {
#pragma unroll
    for (int nt = 0; nt < 4; ++nt) {
#pragma unroll
      for (int i = 0; i < 4; ++i) {
        int r = bm * 128 + wr * 64 + mt * 16 + er + i;
        int c = bn * 128 + wc * 64 + nt * 16 + ec;
        float v = acc[mt][nt][i];
        if constexpr (MODE == 0) {
          int bb = r >> 11, t = r & 2047;
          ((unsigned short*)Cout)[((size_t)bb * LPAD + 3 + t) * DIM + c] = f2bf(v + bias[c]);
        } else if constexpr (MODE == 1) {
          if (r < M2 && c < 48) ((float*)Cout)[(size_t)r * 48 + c] = v;
        } else {
          if (r < M2) ((float*)Cout)[(size_t)r * DMODEL + c] = v + bias[c];
        }
      }
    }
  }
}

// ---------------- delta precompute: softplus(d_raw @ W_dt.T + b_dt) -> bf16 ----------------
__global__ __launch_bounds__(256) void delta_kernel(const float* __restrict__ xdbl,
                                                    const float* __restrict__ W_dt,
                                                    const float* __restrict__ b_dt,
                                                    unsigned short* __restrict__ delta) {
  const int d = blockIdx.y * 256 + threadIdx.x;
  const int r0 = blockIdx.x * 8;
  float wv[16];
  const float4* wp = (const float4*)(W_dt + (size_t)d * 16);
#pragma unroll
  for (int q = 0; q < 4; ++q) {
    float4 t = wp[q];
    wv[q * 4 + 0] = t.x; wv[q * 4 + 1] = t.y; wv[q * 4 + 2] = t.z; wv[q * 4 + 3] = t.w;
  }
  const float bd = b_dt[d];
#pragma unroll
  for (int j = 0; j < 8; ++j) {
    const float* dr = xdbl + (size_t)(r0 + j) * 48;   // uniform -> s_load
    float z0 = bd, z1 = 0.f, z2 = 0.f, z3 = 0.f;
#pragma unroll
    for (int n = 0; n < 16; n += 4) {
      z0 = fmaf(dr[n + 0], wv[n + 0], z0);
      z1 = fmaf(dr[n + 1], wv[n + 1], z1);
      z2 = fmaf(dr[n + 2], wv[n + 2], z2);
      z3 = fmaf(dr[n + 3], wv[n + 3], z3);
    }
    float z = (z0 + z1) + (z2 + z3);
    float dl = (z > 20.f) ? z : __logf(1.f + __expf(z));
    delta[(size_t)(r0 + j) * DIM + d] = f2bf(dl);
  }
}

// ---------------- chunked scan, pass 1: per-chunk (sumd, q) -> bf16 ----------------
__global__ __launch_bounds__(256) void scan_pass1(const unsigned short* __restrict__ xc,
                                                  const unsigned short* __restrict__ dl,
                                                  const float* __restrict__ xd,
                                                  unsigned short* __restrict__ sdbuf,
                                                  unsigned short* __restrict__ qbuf) {
  const int wid = __builtin_amdgcn_readfirstlane((int)(threadIdx.x >> 6));
  const int lane = threadIdx.x & 63;
  const int W = blockIdx.x * 4 + wid;
  const int dg = W & 31;
  const int rest = W >> 5;
  const int c = rest % NCH;
  const int b = rest / NCH;
  const int d = dg * 64 + lane;
  const int t0 = c * CS;
  const int nst = (t0 + CS <= LC) ? CS : (LC - t0);

  float2v A2L[8];
#pragma unroll
  for (int i = 0; i < 8; ++i)
    A2L[i] = (float2v){AeT[2 * i] * LOG2E, AeT[2 * i + 1] * LOG2E};

  float2v h2[8];
#pragma unroll
  for (int i = 0; i < 8; ++i) h2[i] = (float2v){0.f, 0.f};
  float sumd = 0.f;

  const size_t row0 = (size_t)b * LC + t0;
  const float* xdb = xd + row0 * 48 + 16;            // B cols (uniform -> s_load)
  const unsigned short* xcp = xc + row0 * DIM + d;
  const unsigned short* dp  = dl + row0 * DIM + d;

  float2v BA[8], BB[8];
#pragma unroll
  for (int j = 0; j < 8; ++j) BA[j] = *(const float2v*)(xdb + 2 * j);
  float d0v = bf2f(dp[0]), x0v = bf2f(xcp[0]);

  auto step = [&](const float2v (&Bv)[8], float dlt, float xcv) {
    sumd += dlt;
    float2v dlt2 = (float2v){dlt, dlt};
    float2v xcv2 = (float2v){xcv, xcv};
#pragma unroll
    for (int i = 0; i < 8; ++i) {
      float2v arg = pk_mul_vv(dlt2, A2L[i]);
      float e0 = exp2_raw(arg.x), e1 = exp2_raw(arg.y);
      float2v e2 = (float2v){e0, e1};
      h2[i] = pk_fma_vvv(h2[i], e2, pk_mul_sv(Bv[i], xcv2));
    }
  };

  for (int s = 0; s < nst; s += 2) {
    int s1 = (s + 1 < nst) ? s + 1 : s;
#pragma unroll
    for (int j = 0; j < 8; ++j) BB[j] = *(const float2v*)(xdb + (size_t)s1 * 48 + 2 * j);
    float d1v = bf2f(dp[(size_t)s1 * DIM]);
    float x1v = bf2f(xcp[(size_t)s1 * DIM]);
    step(BA, d0v, x0v);
    if (s + 1 >= nst) break;
    int s2 = (s + 2 < nst) ? s + 2 : s + 1;
#pragma unroll
    for (int j = 0; j < 8; ++j) BA[j] = *(const float2v*)(xdb + (size_t)s2 * 48 + 2 * j);
    d0v = bf2f(dp[(size_t)s2 * DIM]);
    x0v = bf2f(xcp[(size_t)s2 * DIM]);
    step(BB, d1v, x1v);
  }

  sdbuf[((size_t)(b * NCH + c) << 11) + d] = f2bf(sumd);
  const size_t base = ((size_t)(b * NCH + c) * 16) * 2048 + d;
#pragma unroll
  for (int i = 0; i < 8; ++i) {
    qbuf[base + ((size_t)(2 * i) << 11)]     = f2bf(h2[i].x);
    qbuf[base + ((size_t)(2 * i + 1) << 11)] = f2bf(h2[i].y);
  }
}

// ---------------- boundary scan: h across chunks; writes h_init over q ----------------
__global__ __launch_bounds__(64) void scan_boundary(const unsigned short* __restrict__ sdbuf,
                                                    unsigned short* __restrict__ qbuf) {
  const int d = blockIdx.x * 64 + threadIdx.x;
  const int b = blockIdx.y;
  float h[16];
#pragma unroll
  for (int n = 0; n < 16; ++n) h[n] = 0.f;
  for (int c = 0; c < NCH; ++c) {
    const float sd = bf2f(sdbuf[((size_t)(b * NCH + c) << 11) + d]);
    const size_t base = ((size_t)(b * NCH + c) * 16) * 2048 + d;
    float qv[16];
#pragma unroll
    for (int n = 0; n < 16; ++n) qv[n] = bf2f(qbuf[base + ((size_t)n << 11)]);
#pragma unroll
    for (int n = 0; n < 16; ++n) {
      float Pv = __expf(sd * AeT[n]);
      qbuf[base + ((size_t)n << 11)] = f2bf(h[n]);   // h at chunk start
      h[n] = fmaf(Pv, h[n], qv[n]);
    }
  }
}

// ---------------- chunked scan, pass 2: recompute with h_init, emit y ----------------
// NOTE: y aliases dl (in-place, same [r][d] layout); per-element load precedes store
// within the owning thread, and no two threads touch the same element.
__global__ __launch_bounds__(256) void scan_pass2(const unsigned short* __restrict__ xc,
                                                  const unsigned short* __restrict__ dl,
                                                  const float* __restrict__ xd,
                                                  const unsigned short* __restrict__ hinit,
                                                  unsigned short* __restrict__ y) {
  const int wid = __builtin_amdgcn_readfirstlane((int)(threadIdx.x >> 6));
  const int lane = threadIdx.x & 63;
  const int W = blockIdx.x * 4 + wid;
  const int dg = W & 31;
  const int rest = W >> 5;
  const int c = rest % NCH;
  const int b = rest / NCH;
  const int d = dg * 64 + lane;
  const int t0 = c * CS;
  const int nst = (t0 + CS <= LC) ? CS : (LC - t0);

  float2v A2L[8];
#pragma unroll
  for (int i = 0; i < 8; ++i)
    A2L[i] = (float2v){AeT[2 * i] * LOG2E, AeT[2 * i + 1] * LOG2E};

  const size_t base = ((size_t)(b * NCH + c) * 16) * 2048 + d;
  float2v h2[8];
#pragma unroll
  for (int i = 0; i < 8; ++i)
    h2[i] = (float2v){bf2f(hinit[base + ((size_t)(2 * i) << 11)]),
                      bf2f(hinit[base + ((size_t)(2 * i + 1) << 11)])};

  const size_t row0 = (size_t)b * LC + t0;
  const float* xdb = xd + row0 * 48 + 16;            // B at [j], C at [16+j]
  const unsigned short* xcp = xc + row0 * DIM + d;
  const unsigned short* dp  = dl + row0 * DIM + d;
  unsigned short* yp = y + row0 * DIM + d;

  float2v BA[8], CA[8], BB[8], CB[8];
#pragma unroll
  for (int j = 0; j < 8; ++j) {
    BA[j] = *(const float2v*)(xdb + 2 * j);
    CA[j] = *(const float2v*)(xdb + 16 + 2 * j);
  }
  float d0v = bf2f(dp[0]), x0v = bf2f(xcp[0]);

  auto step = [&](const float2v (&Bv)[8], const float2v (&Cv)[8], float dlt, float xcv, int s) {
    float2v dlt2 = (float2v){dlt, dlt};
    float2v xcv2 = (float2v){xcv, xcv};
    float2v y2[4];
#pragma unroll
    for (int i = 0; i < 4; ++i) y2[i] = (float2v){0.f, 0.f};
#pragma unroll
    for (int i = 0; i < 8; ++i) {
      float2v arg = pk_mul_vv(dlt2, A2L[i]);
      float e0 = exp2_raw(arg.x), e1 = exp2_raw(arg.y);
      float2v e2 = (float2v){e0, e1};
      h2[i] = pk_fma_vvv(h2[i], e2, pk_mul_sv(Bv[i], xcv2));
      y2[i & 3] = pk_fma_vsv(h2[i], Cv[i], y2[i & 3]);
    }
    float2v s01 = pk_add_vv(y2[0], y2[1]);
    float2v s23 = pk_add_vv(y2[2], y2[3]);
    float2v st = pk_add_vv(s01, s23);
    yp[(size_t)s * DIM] = f2bf(st.x + st.y);
  };

  for (int s = 0; s < nst; s += 2) {
    int s1 = (s + 1 < nst) ? s + 1 : s;
#pragma unroll
    for (int j = 0; j < 8; ++j) {
      BB[j] = *(const float2v*)(xdb + (size_t)s1 * 48 + 2 * j);
      CB[j] = *(const float2v*)(xdb + (size_t)s1 * 48 + 16 + 2 * j);
    }
    float d1v = bf2f(dp[(size_t)s1 * DIM]);
    float x1v = bf2f(xcp[(size_t)s1 * DIM]);
    step(BA, CA, d0v, x0v, s);
    if (s + 1 >= nst) break;
    int s2 = (s + 2 < nst) ? s + 2 : s + 1;
#pragma unroll
    for (int j = 0; j < 8; ++j) {
      BA[j] = *(const float2v*)(xdb + (size_t)s2 * 48 + 2 * j);
      CA[j] = *(const float2v*)(xdb + (size_t)s2 * 48 + 16 + 2 * j);
    }
    d0v = bf2f(dp[(size_t)s2 * DIM]);
    x0v = bf2f(xcp[(size_t)s2 * DIM]);
    step(BB, CB, d1v, x1v, s + 1);
  }
}

// ---------------- launch ----------------
extern "C" void kernel_launch(void* const* d_in, const int* in_sizes, int n_in,
                              void* d_out, int out_size, void* d_ws, size_t ws_size,
                              hipStream_t stream) {
  const float* x      = (const float*)d_in[0];
  const float* W_in   = (const float*)d_in[1];
  const float* b_in   = (const float*)d_in[2];
  const float* conv_w = (const float*)d_in[3];
  const float* conv_b = (const float*)d_in[4];
  const float* W_x    = (const float*)d_in[5];
  const float* W_dt   = (const float*)d_in[6];
  const float* b_dt   = (const float*)d_in[7];
  const float* W_out  = (const float*)d_in[8];
  const float* b_out  = (const float*)d_in[9];

  char* w = (char*)d_ws;
  // region 0 (67.63 MB): xp (LPAD layout) -> delta [M2P][DIM] -> y (in-place over delta)
  unsigned short* xp    = (unsigned short*)w;
  unsigned short* delta = (unsigned short*)w;
  unsigned short* ybuf  = (unsigned short*)w;
  size_t off = (size_t)M2P * DIM * 2;                                  // 67,633,152
  unsigned short* xcb  = (unsigned short*)(w + off); off += (size_t)M2P * DIM * 2;
  size_t xA_off = off;                                                 // 135,266,304
  unsigned short* xA   = (unsigned short*)(w + off); off += (size_t)16384 * 1024 * 2;
  unsigned short* wInB = (unsigned short*)(w + off); off += (size_t)2048 * 1024 * 2;
  unsigned short* wOutB= (unsigned short*)(w + off); off += (size_t)1024 * 2048 * 2;
  unsigned short* wXB  = (unsigned short*)(w + off); off += (size_t)128 * 2048 * 2;
  float* xdbl          = (float*)(w + off);          off += (size_t)M2 * 48 * 4;
  // sdbuf (2.13 MB bf16) + qbuf (34.08 MB bf16) reuse xA+wInB region (dead after gemm1):
  // 2,129,920 + 34,078,720 = 36.21 MB < 37.75 MB available.
  unsigned short* sdbuf = (unsigned short*)(w + xA_off);
  unsigned short* qbuf  = (unsigned short*)(w + xA_off + (size_t)B8 * NCH * 2048 * 2);
  (void)ws_size; (void)in_sizes; (void)n_in; (void)out_size;

  cvt_f32_bf16<<<8192, 256, 0, stream>>>(x, xA, 2097152);
  cvt_f32_bf16<<<1024, 256, 0, stream>>>(W_in, wInB, 262144);
  cvt_f32_bf16<<<1024, 256, 0, stream>>>(W_out, wOutB, 262144);
  cvt_f32_bf16<<<48,   256, 0, stream>>>(W_x, wXB, 12288);
  zero_pads<<<48, 256, 0, stream>>>(xp);

  // grid = 8 * LX * NBN (1D, XCD-banded remap inside)
  gemm_bt<0, 128, 16, 16><<<2048, 256, 0, stream>>>(xA, wInB, b_in, xp, 1024);
  conv_kernel<<<dim3(LC, B8), 256, 0, stream>>>(xp, conv_w, conv_b, xcb);
  gemm_bt<1, 129, 1, 17><<<136, 256, 0, stream>>>(xcb, wXB, nullptr, xdbl, 2048);
  delta_kernel<<<dim3(2051, 8), 256, 0, stream>>>(xdbl, W_dt, b_dt, delta);

  scan_pass1<<<4160, 256, 0, stream>>>(xcb, delta, xdbl, sdbuf, qbuf);
  scan_boundary<<<dim3(32, B8), 64, 0, stream>>>(sdbuf, qbuf);
  scan_pass2<<<4160, 256, 0, stream>>>(xcb, delta, xdbl, qbuf, ybuf);

  gemm_bt<2, 129, 8, 17><<<1088, 256, 0, stream>>>(ybuf, wOutB, b_out, (float*)d_out, 2048);
}